// Round 8
// baseline (871.517 us; speedup 1.0000x reference)
//
#include <hip/hip_runtime.h>
#include <cstdint>
#include <cstddef>

#define NMAX 100000
#define EMAX 300000

typedef __bf16 bf16_t;
typedef __bf16 bf16x8 __attribute__((ext_vector_type(8)));
typedef float f32x4 __attribute__((ext_vector_type(4)));

// Static device scratch (fully rewritten every launch).
__device__ unsigned short g_mega[(size_t)NMAX * 1024];  // [k1|v1|q2|s2] bf16 (token rows)
__device__ unsigned short g_qs [(size_t)NMAX * 512];    // [q1|s1] bf16 (row rows)
__device__ unsigned short g_kv [(size_t)NMAX * 512];    // [k2|v2] bf16 (row rows)
__device__ unsigned short g_eb1[(size_t)EMAX * 256];    // e-proj phase1 bf16
__device__ unsigned short g_eb2[(size_t)EMAX * 256];    // e-proj phase2 bf16
__device__ unsigned short g_bfB[(size_t)NMAX * 256];    // out_row bf16 (kv2 A)
__device__ unsigned short g_bfW[589824];                // transposed bf16 weights
__device__ float g_bias[2560];                          // concat biases
__device__ int   g_deg [NMAX + 1];
__device__ int   g_rowptr[NMAX + 1];
__device__ int   g_cur [NMAX];
__device__ int2  g_perm2[EMAX];                         // (src, eid) per CSR slot
__device__ int   g_bsum[512];

struct P4  { const float* p[4]; };
struct P10 { const float* p[10]; };

__device__ __forceinline__ unsigned short f2bf(float f) {
  unsigned u = __float_as_uint(f);
  return (unsigned short)((u + 0x7fffu + ((u >> 16) & 1u)) >> 16);
}
__device__ __forceinline__ float bf2f(unsigned short h) {
  return __uint_as_float((unsigned)h << 16);
}

// [W0|W1|W2|W3] (each [K,256] f32) -> Wt[NN,K] bf16 transposed.
__global__ __launch_bounds__(256) void wconv4(P4 Ws, unsigned short* __restrict__ Wt,
                                              int K, int NN) {
  int i = blockIdx.x * 256 + threadIdx.x;
  if (i >= NN * K) return;
  int n = i / K, k = i - n * K;
  Wt[i] = f2bf(Ws.p[n >> 8][(size_t)k * 256 + (n & 255)]);
}

// Concatenate 10 bias vectors (256 each) into g_bias.
__global__ __launch_bounds__(256) void bconcat(P10 b, float* __restrict__ out) {
  int i = blockIdx.x * 256 + threadIdx.x;
  if (i < 2560) out[i] = b.p[i >> 8][i & 255];
}

// ---------------- Barrier-free skinny GEMM v2 ----------------
// C[M,NS](bf16) = A[M,K] @ Wt^T + bias. One 128-col W slice in LDS (XOR
// swizzled, 2-way-free). grid = (ceil(M/256) [x, fastest], NS/128 [y, slow])
// so all concurrent blocks stream the SAME chunk-pass over A -> pass 1 from
// HBM, later passes hit L3 (A fits in 256 MB). Each of 8 waves owns 2
// 16-row strips (32 rows): 4 loads in flight per kc step, acc=64 VGPR.
// No barriers in the main loop.
template <int K, int NS, bool AF32>
__global__ __launch_bounds__(512, 4) void gemm_skinny(const void* __restrict__ Av,
                                                      const unsigned short* __restrict__ Wt,
                                                      const float* __restrict__ bias,
                                                      unsigned short* __restrict__ C,
                                                      int M) {
  constexpr int CH = K / 8;            // 16B chunks per W row
  __shared__ __align__(16) unsigned short Wlds[128 * K];
  const int tid = threadIdx.x;
  const int lane = tid & 63, wid = tid >> 6;
  const int colbase = blockIdx.y * 128;
  const int mbase = blockIdx.x * 256;

  // Stage W slice: rows [colbase, colbase+128) of Wt, swizzled.
  {
    const unsigned short* Wg = Wt + (size_t)colbase * K;
#pragma unroll
    for (int it = 0; it < 128 * CH / 512; ++it) {
      int idx = it * 512 + tid;
      int n = idx / CH, c = idx % CH;
      ((bf16x8*)Wlds)[n * CH + (c ^ (n & 7))] = *(const bf16x8*)(Wg + (size_t)n * K + c * 8);
    }
  }
  __syncthreads();

  const int kg = lane >> 4;            // k-group 0..3 within 32-k chunk
  int arow[2];
#pragma unroll
  for (int s = 0; s < 2; ++s) {
    int r = mbase + wid * 32 + s * 16 + (lane & 15);
    arow[s] = (r >= M) ? (M - 1) : r;
  }

  f32x4 acc[2][8] = {};
#pragma unroll
  for (int kc = 0; kc < K / 32; ++kc) {
    bf16x8 af[2];
#pragma unroll
    for (int s = 0; s < 2; ++s) {
      if constexpr (AF32) {
        const float* ap = (const float*)Av + (size_t)arow[s] * K + kc * 32 + kg * 8;
        float4 f0 = *(const float4*)(ap);
        float4 f1 = *(const float4*)(ap + 4);
        af[s][0] = (bf16_t)f0.x; af[s][1] = (bf16_t)f0.y;
        af[s][2] = (bf16_t)f0.z; af[s][3] = (bf16_t)f0.w;
        af[s][4] = (bf16_t)f1.x; af[s][5] = (bf16_t)f1.y;
        af[s][6] = (bf16_t)f1.z; af[s][7] = (bf16_t)f1.w;
      } else {
        af[s] = *(const bf16x8*)((const unsigned short*)Av + (size_t)arow[s] * K + kc * 32 + kg * 8);
      }
    }
#pragma unroll
    for (int s = 0; s < 2; ++s)
#pragma unroll
      for (int fn = 0; fn < 8; ++fn) {
        int n = fn * 16 + (lane & 15);
        int chunk = kc * 4 + kg;
        bf16x8 bf = ((const bf16x8*)Wlds)[n * CH + (chunk ^ (n & 7))];
        acc[s][fn] = __builtin_amdgcn_mfma_f32_16x16x32_bf16(af[s], bf, acc[s][fn], 0, 0, 0);
      }
  }

  // Epilogue: bias + bf16 store. C/D layout: col=lane&15, row=(lane>>4)*4+j.
#pragma unroll
  for (int s = 0; s < 2; ++s) {
    int rbase = mbase + wid * 32 + s * 16 + ((lane >> 4) << 2);
#pragma unroll
    for (int fn = 0; fn < 8; ++fn) {
      int colg = colbase + fn * 16 + (lane & 15);
      float bv = bias[colg];
#pragma unroll
      for (int j = 0; j < 4; ++j) {
        int row = rbase + j;
        if (row < M) C[(size_t)row * NS + colg] = f2bf(acc[s][fn][j] + bv);
      }
    }
  }
}

// ---------------- CSR build ----------------
__global__ __launch_bounds__(256) void hist_kernel(const int* __restrict__ ei,
                                                   int* __restrict__ deg, int E) {
  int i = blockIdx.x * 256 + threadIdx.x;
  if (i < E) atomicAdd(&deg[ei[E + i]], 1);
}

__global__ __launch_bounds__(256) void scan1(const int* __restrict__ deg,
                                             int* __restrict__ rowptr,
                                             int* __restrict__ bsum, int n) {
  __shared__ int ws[4];
  int i = blockIdx.x * 256 + threadIdx.x;
  int v = (i < n) ? deg[i] : 0;
  int lane = threadIdx.x & 63, wid = threadIdx.x >> 6;
  int inc = v;
#pragma unroll
  for (int o = 1; o < 64; o <<= 1) {
    int t = __shfl_up(inc, o);
    if (lane >= o) inc += t;
  }
  if (lane == 63) ws[wid] = inc;
  __syncthreads();
  int woff = 0;
  if (wid > 0) woff += ws[0];
  if (wid > 1) woff += ws[1];
  if (wid > 2) woff += ws[2];
  if (i < n) rowptr[i] = inc - v + woff;
  if (threadIdx.x == 255) bsum[blockIdx.x] = inc + woff;
}

__global__ __launch_bounds__(512) void scan2(int* __restrict__ bsum, int B) {
  __shared__ int s[512];
  int t = threadIdx.x;
  int v = (t < B) ? bsum[t] : 0;
  s[t] = v;
  __syncthreads();
  for (int o = 1; o < 512; o <<= 1) {
    int a = (t >= o) ? s[t - o] : 0;
    __syncthreads();
    s[t] += a;
    __syncthreads();
  }
  if (t < B) bsum[t] = s[t] - v;
}

__global__ __launch_bounds__(256) void scan3(int* __restrict__ rowptr,
                                             const int* __restrict__ bsum,
                                             const int* __restrict__ deg,
                                             int* __restrict__ cur, int n) {
  int i = blockIdx.x * 256 + threadIdx.x;
  if (i < n) {
    int r = rowptr[i] + bsum[blockIdx.x];
    rowptr[i] = r;
    cur[i] = r;
    if (i == n - 1) rowptr[n] = r + deg[i];
  }
}

__global__ __launch_bounds__(256) void scatter_kernel(const int* __restrict__ ei,
                                                      int* __restrict__ cur,
                                                      int2* __restrict__ perm2, int E) {
  int i = blockIdx.x * 256 + threadIdx.x;
  if (i < E) {
    int s = ei[i];
    int d = ei[E + i];
    int pos = atomicAdd(&cur[d], 1);
    perm2[pos] = make_int2(s, i);
  }
}

// ---------------- Fused attention + skip + residual + LN (bf16 streams) ---
// qs rows: q at +0, s at +256, row stride qs_stride.
// kv rows: k at +0, v at +256, row stride kv_stride.
__global__ __launch_bounds__(256) void fused_attn_ln(
    const int* __restrict__ rowptr, const int2* __restrict__ perm2,
    const unsigned short* __restrict__ qs, int qs_stride,
    const unsigned short* __restrict__ kv, int kv_stride,
    const unsigned short* __restrict__ eb,
    const float* __restrict__ x,
    const float* __restrict__ gamma, const float* __restrict__ beta,
    float* __restrict__ out, unsigned short* __restrict__ out_bf, int N) {
  int node = blockIdx.x * 4 + (threadIdx.x >> 6);
  if (node >= N) return;
  int lane = threadIdx.x & 63;
  int c4 = lane << 2;
  ushort4 qu = *(const ushort4*)(qs + (size_t)node * qs_stride + c4);
  ushort4 su = *(const ushort4*)(qs + (size_t)node * qs_stride + 256 + c4);
  size_t base = (size_t)node * 256 + c4;
  float4 xv = *(const float4*)(x + base);
  float4 qv = make_float4(bf2f(qu.x), bf2f(qu.y), bf2f(qu.z), bf2f(qu.w));
  float4 acc = make_float4(0.f, 0.f, 0.f, 0.f);
  float m = -1e30f, den = 0.f;
  int beg = rowptr[node], end = rowptr[node + 1];
  int2 se = (beg < end) ? perm2[beg] : make_int2(0, 0);
  ushort4 ku = *(const ushort4*)(kv + (size_t)se.x * kv_stride + c4);
  ushort4 vu = *(const ushort4*)(kv + (size_t)se.x * kv_stride + 256 + c4);
  ushort4 eu = *(const ushort4*)(eb + (size_t)se.y * 256 + c4);
  for (int p_ = beg; p_ < end; ++p_) {
    int2 seN = (p_ + 1 < end) ? perm2[p_ + 1] : se;
    ushort4 kuN = *(const ushort4*)(kv + (size_t)seN.x * kv_stride + c4);
    ushort4 vuN = *(const ushort4*)(kv + (size_t)seN.x * kv_stride + 256 + c4);
    ushort4 euN = *(const ushort4*)(eb + (size_t)seN.y * 256 + c4);
    float e0 = bf2f(eu.x), e1 = bf2f(eu.y), e2 = bf2f(eu.z), e3 = bf2f(eu.w);
    float p = qv.x * (bf2f(ku.x) + e0) + qv.y * (bf2f(ku.y) + e1) +
              qv.z * (bf2f(ku.z) + e2) + qv.w * (bf2f(ku.w) + e3);
    p += __shfl_xor(p, 1); p += __shfl_xor(p, 2);
    p += __shfl_xor(p, 4); p += __shfl_xor(p, 8);
    p *= 0.125f;                      // SCALE = 1/sqrt(64)
    float mn = fmaxf(m, p);
    float sc = expf(m - mn);
    float w  = expf(p - mn);
    den = den * sc + w;
    acc.x = acc.x * sc + w * (bf2f(vu.x) + e0);
    acc.y = acc.y * sc + w * (bf2f(vu.y) + e1);
    acc.z = acc.z * sc + w * (bf2f(vu.z) + e2);
    acc.w = acc.w * sc + w * (bf2f(vu.w) + e3);
    m = mn;
    ku = kuN; vu = vuN; eu = euN; se = seN;
  }
  float inv = (den > 0.f) ? 1.0f / den : 0.f;
  float4 val = make_float4(xv.x + bf2f(su.x) + acc.x * inv,
                           xv.y + bf2f(su.y) + acc.y * inv,
                           xv.z + bf2f(su.z) + acc.z * inv,
                           xv.w + bf2f(su.w) + acc.w * inv);
  float t = val.x + val.y + val.z + val.w;
#pragma unroll
  for (int o = 1; o < 64; o <<= 1) t += __shfl_xor(t, o);
  float mean = t * (1.0f / 256.0f);
  float d0 = val.x - mean, d1 = val.y - mean, d2 = val.z - mean, d3 = val.w - mean;
  float ss = d0 * d0 + d1 * d1 + d2 * d2 + d3 * d3;
#pragma unroll
  for (int o = 1; o < 64; o <<= 1) ss += __shfl_xor(ss, o);
  float rstd = rsqrtf(ss * (1.0f / 256.0f) + 1e-5f);
  float4 gv = *(const float4*)(gamma + c4);
  float4 bv = *(const float4*)(beta + c4);
  float4 o4 = make_float4(d0 * rstd * gv.x + bv.x, d1 * rstd * gv.y + bv.y,
                          d2 * rstd * gv.z + bv.z, d3 * rstd * gv.w + bv.w);
  *(float4*)(out + base) = o4;
  if (out_bf) {
    ushort4 ob = make_ushort4(f2bf(o4.x), f2bf(o4.y), f2bf(o4.z), f2bf(o4.w));
    *(ushort4*)(out_bf + base) = ob;
  }
}

extern "C" void kernel_launch(void* const* d_in, const int* in_sizes, int n_in,
                              void* d_out, int out_size, void* d_ws, size_t ws_size,
                              hipStream_t stream) {
  const float* row_x   = (const float*)d_in[0];
  const float* token_x = (const float*)d_in[1];
  const int*   ei1     = (const int*)d_in[2];    // int32 (JAX x64 disabled)
  const float* ea1     = (const float*)d_in[3];
  const int*   ei2     = (const int*)d_in[4];
  const float* ea2     = (const float*)d_in[5];

  const float* W1q = (const float*)d_in[6];  const float* b1q = (const float*)d_in[7];
  const float* W1k = (const float*)d_in[8];  const float* b1k = (const float*)d_in[9];
  const float* W1v = (const float*)d_in[10]; const float* b1v = (const float*)d_in[11];
  const float* W1e = (const float*)d_in[12]; const float* b1e = (const float*)d_in[13];
  const float* W1s = (const float*)d_in[14]; const float* b1s = (const float*)d_in[15];
  const float* W2q = (const float*)d_in[16]; const float* b2q = (const float*)d_in[17];
  const float* W2k = (const float*)d_in[18]; const float* b2k = (const float*)d_in[19];
  const float* W2v = (const float*)d_in[20]; const float* b2v = (const float*)d_in[21];
  const float* W2e = (const float*)d_in[22]; const float* b2e = (const float*)d_in[23];
  const float* W2s = (const float*)d_in[24]; const float* b2s = (const float*)d_in[25];
  const float* row_gamma   = (const float*)d_in[26];
  const float* row_beta    = (const float*)d_in[27];
  const float* token_gamma = (const float*)d_in[28];
  const float* token_beta  = (const float*)d_in[29];

  const int NR = in_sizes[0] / 256;   // 20000
  const int NT = in_sizes[1] / 256;   // 100000
  const int E  = in_sizes[2] / 2;     // 300000

  float* out_row = (float*)d_out;
  float* out_tok = (float*)d_out + (long long)NR * 256;

  void *pmega_, *pqs_, *pkv_, *peb1_, *peb2_, *pbfB_, *pbfW_, *pbias_,
       *pdeg_, *prp_, *pcur_, *pperm_, *pbs_;
  hipGetSymbolAddress(&pmega_,HIP_SYMBOL(g_mega));
  hipGetSymbolAddress(&pqs_,  HIP_SYMBOL(g_qs));
  hipGetSymbolAddress(&pkv_,  HIP_SYMBOL(g_kv));
  hipGetSymbolAddress(&peb1_, HIP_SYMBOL(g_eb1));
  hipGetSymbolAddress(&peb2_, HIP_SYMBOL(g_eb2));
  hipGetSymbolAddress(&pbfB_, HIP_SYMBOL(g_bfB));
  hipGetSymbolAddress(&pbfW_, HIP_SYMBOL(g_bfW));
  hipGetSymbolAddress(&pbias_,HIP_SYMBOL(g_bias));
  hipGetSymbolAddress(&pdeg_, HIP_SYMBOL(g_deg));
  hipGetSymbolAddress(&prp_,  HIP_SYMBOL(g_rowptr));
  hipGetSymbolAddress(&pcur_, HIP_SYMBOL(g_cur));
  hipGetSymbolAddress(&pperm_,HIP_SYMBOL(g_perm2));
  hipGetSymbolAddress(&pbs_,  HIP_SYMBOL(g_bsum));
  unsigned short* mega = (unsigned short*)pmega_;
  unsigned short* qs   = (unsigned short*)pqs_;
  unsigned short* kv   = (unsigned short*)pkv_;
  unsigned short* eb1  = (unsigned short*)peb1_;
  unsigned short* eb2  = (unsigned short*)peb2_;
  unsigned short* bfB  = (unsigned short*)pbfB_;
  unsigned short* bfW  = (unsigned short*)pbfW_;
  float* gbias = (float*)pbias_;
  int*   deg   = (int*)pdeg_;
  int*   rp    = (int*)prp_;
  int*   cur   = (int*)pcur_;
  int2*  perm2 = (int2*)pperm_;
  int*   bsum  = (int*)pbs_;

  // Weight buffers (elements): Wmega@0 (1024x256), Wqs1@262144 (512x256),
  // Wkv2@393216 (512x256), We1@524288 (256x128), We2@557056 (256x128).
  unsigned short* Wmega = bfW + 0;
  unsigned short* Wqs1  = bfW + 262144;
  unsigned short* Wkv2  = bfW + 393216;
  unsigned short* We1   = bfW + 524288;
  unsigned short* We2   = bfW + 557056;
  wconv4<<<1024, 256, 0, stream>>>(P4{{W1k, W1v, W2q, W2s}}, Wmega, 256, 1024);
  wconv4<<<512, 256, 0, stream>>>(P4{{W1q, W1s, nullptr, nullptr}}, Wqs1, 256, 512);
  wconv4<<<512, 256, 0, stream>>>(P4{{W2k, W2v, nullptr, nullptr}}, Wkv2, 256, 512);
  wconv4<<<128, 256, 0, stream>>>(P4{{W1e, nullptr, nullptr, nullptr}}, We1, 128, 256);
  wconv4<<<128, 256, 0, stream>>>(P4{{W2e, nullptr, nullptr, nullptr}}, We2, 128, 256);
  // Bias layout: mega [b1k|b1v|b2q|b2s]@0, [b1q|b1s]@1024, [b2k|b2v]@1536,
  // b1e@2048, b2e@2304.
  P10 bp{{b1k, b1v, b2q, b2s, b1q, b1s, b2k, b2v, b1e, b2e}};
  bconcat<<<10, 256, 0, stream>>>(bp, gbias);

  const int egrid = (E + 255) / 256;

  auto csr = [&](const int* ei, int Ndst) {
    hipMemsetAsync(deg, 0, (size_t)(Ndst + 1) * sizeof(int), stream);
    hist_kernel<<<egrid, 256, 0, stream>>>(ei, deg, E);
    int B = (Ndst + 255) / 256;
    scan1<<<B, 256, 0, stream>>>(deg, rp, bsum, Ndst);
    scan2<<<1, 512, 0, stream>>>(bsum, B);
    scan3<<<B, 256, 0, stream>>>(rp, bsum, deg, cur, Ndst);
    scatter_kernel<<<egrid, 256, 0, stream>>>(ei, cur, perm2, E);
  };

  // ---------------- Projection GEMMs (m fastest, chunk slow) ----------------
  gemm_skinny<256, 1024, true><<<dim3((NT + 255) / 256, 8), 512, 0, stream>>>(
      token_x, Wmega, gbias + 0, mega, NT);
  gemm_skinny<256, 512, true><<<dim3((NR + 255) / 256, 4), 512, 0, stream>>>(
      row_x, Wqs1, gbias + 1024, qs, NR);
  gemm_skinny<128, 256, true><<<dim3((E + 255) / 256, 2), 512, 0, stream>>>(
      ea1, We1, gbias + 2048, eb1, E);
  gemm_skinny<128, 256, true><<<dim3((E + 255) / 256, 2), 512, 0, stream>>>(
      ea2, We2, gbias + 2304, eb2, E);

  // ---------------- Phase 1: t2r ----------------
  csr(ei1, NR);
  fused_attn_ln<<<(NR + 3) / 4, 256, 0, stream>>>(rp, perm2,
                                                  qs, 512, mega, 1024, eb1,
                                                  row_x, row_gamma, row_beta,
                                                  out_row, bfB, NR);

  // ---------------- Phase 2: r2t ----------------
  gemm_skinny<256, 512, false><<<dim3((NR + 255) / 256, 4), 512, 0, stream>>>(
      bfB, Wkv2, gbias + 1536, kv, NR);
  csr(ei2, NT);
  fused_attn_ln<<<(NT + 3) / 4, 256, 0, stream>>>(rp, perm2,
                                                  mega + 512, 1024, kv, 512, eb2,
                                                  token_x, token_gamma, token_beta,
                                                  out_tok, nullptr, NT);
}

// Round 9
// 682.237 us; speedup vs baseline: 1.2774x; 1.2774x over previous
//
#include <hip/hip_runtime.h>
#include <cstdint>
#include <cstddef>

#define NMAX 100000
#define EMAX 300000

typedef __bf16 bf16_t;
typedef __bf16 bf16x8 __attribute__((ext_vector_type(8)));
typedef float f32x4 __attribute__((ext_vector_type(4)));
typedef unsigned int u32;

// Static device scratch (fully rewritten every launch).
__device__ unsigned short g_mega[(size_t)NMAX * 1024];  // [k1|v1|q2|s2] bf16 (token rows)
__device__ unsigned short g_qs [(size_t)NMAX * 512];    // [q1|s1] bf16 (row rows)
__device__ unsigned short g_kv [(size_t)NMAX * 512];    // [k2|v2] bf16 (row rows)
__device__ unsigned short g_eb1[(size_t)EMAX * 256];    // e-proj phase1 bf16
__device__ unsigned short g_eb2[(size_t)EMAX * 256];    // e-proj phase2 bf16
__device__ unsigned short g_bfA[(size_t)NMAX * 256];    // token_x bf16
__device__ unsigned short g_bfB[(size_t)NMAX * 256];    // row_x bf16 -> out_row bf16
__device__ unsigned short g_bfE1[(size_t)EMAX * 128];   // edge_attr1 bf16
__device__ unsigned short g_bfE2[(size_t)EMAX * 128];   // edge_attr2 bf16
__device__ unsigned short g_bfW[589824];                // transposed bf16 weights
__device__ float g_bias[2560];                          // concat biases
__device__ int   g_deg [NMAX + 1];
__device__ int   g_rowptr[NMAX + 1];
__device__ int   g_cur [NMAX];
__device__ int2  g_perm2[EMAX];                         // (src, eid) per CSR slot
__device__ int   g_bsum[512];

struct P4  { const float* p[4]; };
struct P10 { const float* p[10]; };

__device__ __forceinline__ unsigned short f2bf(float f) {
  unsigned u = __float_as_uint(f);
  return (unsigned short)((u + 0x7fffu + ((u >> 16) & 1u)) >> 16);
}
__device__ __forceinline__ void dec8(uint4 u, float* f) {
  f[0] = __uint_as_float(u.x << 16); f[1] = __uint_as_float(u.x & 0xffff0000u);
  f[2] = __uint_as_float(u.y << 16); f[3] = __uint_as_float(u.y & 0xffff0000u);
  f[4] = __uint_as_float(u.z << 16); f[5] = __uint_as_float(u.z & 0xffff0000u);
  f[6] = __uint_as_float(u.w << 16); f[7] = __uint_as_float(u.w & 0xffff0000u);
}

// f32 -> bf16, 8 elems/thread.
__global__ __launch_bounds__(256) void conv_bf16(const float* __restrict__ in,
                                                 unsigned short* __restrict__ out,
                                                 long long n8) {
  long long i = (long long)blockIdx.x * 256 + threadIdx.x;
  if (i >= n8) return;
  const float4* p = (const float4*)(in + i * 8);
  float4 a = p[0], b = p[1];
  ushort4 lo = make_ushort4(f2bf(a.x), f2bf(a.y), f2bf(a.z), f2bf(a.w));
  ushort4 hi = make_ushort4(f2bf(b.x), f2bf(b.y), f2bf(b.z), f2bf(b.w));
  ushort4* q = (ushort4*)(out + i * 8);
  q[0] = lo; q[1] = hi;
}

// [W0|W1|W2|W3] (each [K,256] f32) -> Wt[NN,K] bf16 transposed.
__global__ __launch_bounds__(256) void wconv4(P4 Ws, unsigned short* __restrict__ Wt,
                                              int K, int NN) {
  int i = blockIdx.x * 256 + threadIdx.x;
  if (i >= NN * K) return;
  int n = i / K, k = i - n * K;
  Wt[i] = f2bf(Ws.p[n >> 8][(size_t)k * 256 + (n & 255)]);
}

// Concatenate 10 bias vectors (256 each) into g_bias.
__global__ __launch_bounds__(256) void bconcat(P10 b, float* __restrict__ out) {
  int i = blockIdx.x * 256 + threadIdx.x;
  if (i < 2560) out[i] = b.p[i >> 8][i & 255];
}

#define GLL16(gp, lp) __builtin_amdgcn_global_load_lds( \
    (const __attribute__((address_space(1))) void*)(gp), \
    (__attribute__((address_space(3))) void*)(lp), 16, 0, 0)

// C[M,NS](bf16) = bf16(A[M,K]) @ Wt^T + bias ; 128x128 tile, BK=64, 4 waves,
// 16x16x32 bf16 MFMA, global_load_lds + XOR swizzle both sides.
// (round-5 proven structure)
template <int K, int NS>
__global__ __launch_bounds__(256) void gemm_mfma(const unsigned short* __restrict__ A,
                                                 const unsigned short* __restrict__ Bt,
                                                 const float* __restrict__ bias,
                                                 unsigned short* __restrict__ C, int M) {
  __shared__ unsigned short As[128 * 64];
  __shared__ unsigned short Bs[128 * 64];
  const int tid = threadIdx.x;
  const int lane = tid & 63, wid = tid >> 6;
  const int bm = blockIdx.x * 128, bn = blockIdx.y * 128;
  const int wrow = (wid & 1) * 64, wcol = (wid >> 1) * 64;
  const int sr = lane >> 3;
  const int slot = lane & 7;

  f32x4 acc[4][4] = {};

  for (int k0 = 0; k0 < K; k0 += 64) {
#pragma unroll
    for (int r = 0; r < 4; ++r) {
      int row = (wid * 4 + r) * 8 + sr;
      int arow = bm + row; if (arow >= M) arow = M - 1;
      int kk = k0 + ((slot ^ (row & 7)) << 3);
      GLL16(A + (size_t)arow * K + kk, (unsigned short*)As + (size_t)(wid * 4 + r) * 512);
    }
#pragma unroll
    for (int r = 0; r < 4; ++r) {
      int col = (wid * 4 + r) * 8 + sr;
      int kk = k0 + ((slot ^ (col & 7)) << 3);
      GLL16(Bt + (size_t)(bn + col) * K + kk, (unsigned short*)Bs + (size_t)(wid * 4 + r) * 512);
    }
    __syncthreads();
    const char* Ab = (const char*)As;
    const char* Bb = (const char*)Bs;
#pragma unroll
    for (int h = 0; h < 2; ++h) {
      bf16x8 af[4], bfr[4];
      int g = (lane >> 4) + h * 4;
#pragma unroll
      for (int fm = 0; fm < 4; ++fm) {
        int row = wrow + fm * 16 + (lane & 15);
        af[fm] = *(const bf16x8*)(Ab + row * 128 + ((g ^ (row & 7)) << 4));
      }
#pragma unroll
      for (int fn = 0; fn < 4; ++fn) {
        int col = wcol + fn * 16 + (lane & 15);
        bfr[fn] = *(const bf16x8*)(Bb + col * 128 + ((g ^ (col & 7)) << 4));
      }
#pragma unroll
      for (int fm = 0; fm < 4; ++fm)
#pragma unroll
        for (int fn = 0; fn < 4; ++fn)
          acc[fm][fn] = __builtin_amdgcn_mfma_f32_16x16x32_bf16(af[fm], bfr[fn],
                                                                acc[fm][fn], 0, 0, 0);
    }
    __syncthreads();
  }
  // Epilogue: bias + bf16 store, fn innermost for write locality.
  float bv[4];
#pragma unroll
  for (int fn = 0; fn < 4; ++fn) bv[fn] = bias[bn + wcol + fn * 16 + (lane & 15)];
#pragma unroll
  for (int fm = 0; fm < 4; ++fm) {
    int rbase = bm + wrow + fm * 16 + ((lane >> 4) << 2);
#pragma unroll
    for (int j = 0; j < 4; ++j) {
      int row = rbase + j;
      if (row < M) {
        size_t rb = (size_t)row * NS + bn + wcol + (lane & 15);
#pragma unroll
        for (int fn = 0; fn < 4; ++fn)
          C[rb + fn * 16] = f2bf(acc[fm][fn][j] + bv[fn]);
      }
    }
  }
}

// ---------------- CSR build ----------------
__global__ __launch_bounds__(256) void hist_kernel(const int* __restrict__ ei,
                                                   int* __restrict__ deg, int E) {
  int i = blockIdx.x * 256 + threadIdx.x;
  if (i < E) atomicAdd(&deg[ei[E + i]], 1);
}

__global__ __launch_bounds__(256) void scan1(const int* __restrict__ deg,
                                             int* __restrict__ rowptr,
                                             int* __restrict__ bsum, int n) {
  __shared__ int ws[4];
  int i = blockIdx.x * 256 + threadIdx.x;
  int v = (i < n) ? deg[i] : 0;
  int lane = threadIdx.x & 63, wid = threadIdx.x >> 6;
  int inc = v;
#pragma unroll
  for (int o = 1; o < 64; o <<= 1) {
    int t = __shfl_up(inc, o);
    if (lane >= o) inc += t;
  }
  if (lane == 63) ws[wid] = inc;
  __syncthreads();
  int woff = 0;
  if (wid > 0) woff += ws[0];
  if (wid > 1) woff += ws[1];
  if (wid > 2) woff += ws[2];
  if (i < n) rowptr[i] = inc - v + woff;
  if (threadIdx.x == 255) bsum[blockIdx.x] = inc + woff;
}

__global__ __launch_bounds__(512) void scan2(int* __restrict__ bsum, int B) {
  __shared__ int s[512];
  int t = threadIdx.x;
  int v = (t < B) ? bsum[t] : 0;
  s[t] = v;
  __syncthreads();
  for (int o = 1; o < 512; o <<= 1) {
    int a = (t >= o) ? s[t - o] : 0;
    __syncthreads();
    s[t] += a;
    __syncthreads();
  }
  if (t < B) bsum[t] = s[t] - v;
}

__global__ __launch_bounds__(256) void scan3(int* __restrict__ rowptr,
                                             const int* __restrict__ bsum,
                                             const int* __restrict__ deg,
                                             int* __restrict__ cur, int n) {
  int i = blockIdx.x * 256 + threadIdx.x;
  if (i < n) {
    int r = rowptr[i] + bsum[blockIdx.x];
    rowptr[i] = r;
    cur[i] = r;
    if (i == n - 1) rowptr[n] = r + deg[i];
  }
}

__global__ __launch_bounds__(256) void scatter_kernel(const int* __restrict__ ei,
                                                      int* __restrict__ cur,
                                                      int2* __restrict__ perm2, int E) {
  int i = blockIdx.x * 256 + threadIdx.x;
  if (i < E) {
    int s = ei[i];
    int d = ei[E + i];
    int pos = atomicAdd(&cur[d], 1);
    perm2[pos] = make_int2(s, i);
  }
}

// ---------------- Fused attention + skip + residual + LN (v2) ----------------
// 32 lanes per dst node (8 channels/lane, head = 8 lanes); 2 nodes/wave,
// 8 nodes/block. uint4 (16B) bf16 loads. 2-deep software-pipelined edge loop.
__global__ __launch_bounds__(256) void fused_attn_ln(
    const int* __restrict__ rowptr, const int2* __restrict__ perm2,
    const unsigned short* __restrict__ qs, int qs_stride,
    const unsigned short* __restrict__ kv, int kv_stride,
    const unsigned short* __restrict__ eb,
    const float* __restrict__ x,
    const float* __restrict__ gamma, const float* __restrict__ beta,
    float* __restrict__ out, unsigned short* __restrict__ out_bf, int N) {
  int node = blockIdx.x * 8 + (threadIdx.x >> 5);
  if (node >= N) return;
  int sub = threadIdx.x & 31;
  int c8 = sub << 3;
  uint4 qu = *(const uint4*)(qs + (size_t)node * qs_stride + c8);
  uint4 su = *(const uint4*)(qs + (size_t)node * qs_stride + 256 + c8);
  size_t base = (size_t)node * 256 + c8;
  float4 xv0 = *(const float4*)(x + base);
  float4 xv1 = *(const float4*)(x + base + 4);
  float q[8], s[8];
  dec8(qu, q); dec8(su, s);
  float acc[8] = {0.f, 0.f, 0.f, 0.f, 0.f, 0.f, 0.f, 0.f};
  float m = -1e30f, den = 0.f;
  int beg = rowptr[node], end = rowptr[node + 1];
  int2 se = (beg < end) ? perm2[beg] : make_int2(0, 0);
  uint4 ku = *(const uint4*)(kv + (size_t)se.x * kv_stride + c8);
  uint4 vu = *(const uint4*)(kv + (size_t)se.x * kv_stride + 256 + c8);
  uint4 eu = *(const uint4*)(eb + (size_t)se.y * 256 + c8);
  for (int p_ = beg; p_ < end; ++p_) {
    int2 seN = (p_ + 1 < end) ? perm2[p_ + 1] : se;
    uint4 kuN = *(const uint4*)(kv + (size_t)seN.x * kv_stride + c8);
    uint4 vuN = *(const uint4*)(kv + (size_t)seN.x * kv_stride + 256 + c8);
    uint4 euN = *(const uint4*)(eb + (size_t)seN.y * 256 + c8);
    float kf[8], vf[8], ef[8];
    dec8(ku, kf); dec8(vu, vf); dec8(eu, ef);
    float p = 0.f;
#pragma unroll
    for (int j = 0; j < 8; ++j) p += q[j] * (kf[j] + ef[j]);
    p += __shfl_xor(p, 1); p += __shfl_xor(p, 2); p += __shfl_xor(p, 4);
    p *= 0.125f;                      // SCALE = 1/sqrt(64)
    float mn = fmaxf(m, p);
    float sc = expf(m - mn);
    float w  = expf(p - mn);
    den = den * sc + w;
#pragma unroll
    for (int j = 0; j < 8; ++j) acc[j] = acc[j] * sc + w * (vf[j] + ef[j]);
    m = mn;
    ku = kuN; vu = vuN; eu = euN; se = seN;
  }
  float inv = (den > 0.f) ? 1.0f / den : 0.f;
  float val[8];
  val[0] = xv0.x + s[0] + acc[0] * inv; val[1] = xv0.y + s[1] + acc[1] * inv;
  val[2] = xv0.z + s[2] + acc[2] * inv; val[3] = xv0.w + s[3] + acc[3] * inv;
  val[4] = xv1.x + s[4] + acc[4] * inv; val[5] = xv1.y + s[5] + acc[5] * inv;
  val[6] = xv1.z + s[6] + acc[6] * inv; val[7] = xv1.w + s[7] + acc[7] * inv;
  float t = 0.f;
#pragma unroll
  for (int j = 0; j < 8; ++j) t += val[j];
#pragma unroll
  for (int o = 1; o < 32; o <<= 1) t += __shfl_xor(t, o);
  float mean = t * (1.0f / 256.0f);
  float d[8], ss = 0.f;
#pragma unroll
  for (int j = 0; j < 8; ++j) { d[j] = val[j] - mean; ss += d[j] * d[j]; }
#pragma unroll
  for (int o = 1; o < 32; o <<= 1) ss += __shfl_xor(ss, o);
  float rstd = rsqrtf(ss * (1.0f / 256.0f) + 1e-5f);
  float4 g0 = *(const float4*)(gamma + c8);
  float4 g1 = *(const float4*)(gamma + c8 + 4);
  float4 b0 = *(const float4*)(beta + c8);
  float4 b1 = *(const float4*)(beta + c8 + 4);
  float o8[8];
  o8[0] = d[0] * rstd * g0.x + b0.x; o8[1] = d[1] * rstd * g0.y + b0.y;
  o8[2] = d[2] * rstd * g0.z + b0.z; o8[3] = d[3] * rstd * g0.w + b0.w;
  o8[4] = d[4] * rstd * g1.x + b1.x; o8[5] = d[5] * rstd * g1.y + b1.y;
  o8[6] = d[6] * rstd * g1.z + b1.z; o8[7] = d[7] * rstd * g1.w + b1.w;
  *(float4*)(out + base)     = make_float4(o8[0], o8[1], o8[2], o8[3]);
  *(float4*)(out + base + 4) = make_float4(o8[4], o8[5], o8[6], o8[7]);
  if (out_bf) {
    uint4 ob;
    ob.x = (u32)f2bf(o8[0]) | ((u32)f2bf(o8[1]) << 16);
    ob.y = (u32)f2bf(o8[2]) | ((u32)f2bf(o8[3]) << 16);
    ob.z = (u32)f2bf(o8[4]) | ((u32)f2bf(o8[5]) << 16);
    ob.w = (u32)f2bf(o8[6]) | ((u32)f2bf(o8[7]) << 16);
    *(uint4*)(out_bf + base) = ob;
  }
}

extern "C" void kernel_launch(void* const* d_in, const int* in_sizes, int n_in,
                              void* d_out, int out_size, void* d_ws, size_t ws_size,
                              hipStream_t stream) {
  const float* row_x   = (const float*)d_in[0];
  const float* token_x = (const float*)d_in[1];
  const int*   ei1     = (const int*)d_in[2];    // int32 (JAX x64 disabled)
  const float* ea1     = (const float*)d_in[3];
  const int*   ei2     = (const int*)d_in[4];
  const float* ea2     = (const float*)d_in[5];

  const float* W1q = (const float*)d_in[6];  const float* b1q = (const float*)d_in[7];
  const float* W1k = (const float*)d_in[8];  const float* b1k = (const float*)d_in[9];
  const float* W1v = (const float*)d_in[10]; const float* b1v = (const float*)d_in[11];
  const float* W1e = (const float*)d_in[12]; const float* b1e = (const float*)d_in[13];
  const float* W1s = (const float*)d_in[14]; const float* b1s = (const float*)d_in[15];
  const float* W2q = (const float*)d_in[16]; const float* b2q = (const float*)d_in[17];
  const float* W2k = (const float*)d_in[18]; const float* b2k = (const float*)d_in[19];
  const float* W2v = (const float*)d_in[20]; const float* b2v = (const float*)d_in[21];
  const float* W2e = (const float*)d_in[22]; const float* b2e = (const float*)d_in[23];
  const float* W2s = (const float*)d_in[24]; const float* b2s = (const float*)d_in[25];
  const float* row_gamma   = (const float*)d_in[26];
  const float* row_beta    = (const float*)d_in[27];
  const float* token_gamma = (const float*)d_in[28];
  const float* token_beta  = (const float*)d_in[29];

  const int NR = in_sizes[0] / 256;   // 20000
  const int NT = in_sizes[1] / 256;   // 100000
  const int E  = in_sizes[2] / 2;     // 300000

  float* out_row = (float*)d_out;
  float* out_tok = (float*)d_out + (long long)NR * 256;

  void *pmega_, *pqs_, *pkv_, *peb1_, *peb2_, *pbfA_, *pbfB_, *pbfE1_, *pbfE2_,
       *pbfW_, *pbias_, *pdeg_, *prp_, *pcur_, *pperm_, *pbs_;
  hipGetSymbolAddress(&pmega_, HIP_SYMBOL(g_mega));
  hipGetSymbolAddress(&pqs_,   HIP_SYMBOL(g_qs));
  hipGetSymbolAddress(&pkv_,   HIP_SYMBOL(g_kv));
  hipGetSymbolAddress(&peb1_,  HIP_SYMBOL(g_eb1));
  hipGetSymbolAddress(&peb2_,  HIP_SYMBOL(g_eb2));
  hipGetSymbolAddress(&pbfA_,  HIP_SYMBOL(g_bfA));
  hipGetSymbolAddress(&pbfB_,  HIP_SYMBOL(g_bfB));
  hipGetSymbolAddress(&pbfE1_, HIP_SYMBOL(g_bfE1));
  hipGetSymbolAddress(&pbfE2_, HIP_SYMBOL(g_bfE2));
  hipGetSymbolAddress(&pbfW_,  HIP_SYMBOL(g_bfW));
  hipGetSymbolAddress(&pbias_, HIP_SYMBOL(g_bias));
  hipGetSymbolAddress(&pdeg_,  HIP_SYMBOL(g_deg));
  hipGetSymbolAddress(&prp_,   HIP_SYMBOL(g_rowptr));
  hipGetSymbolAddress(&pcur_,  HIP_SYMBOL(g_cur));
  hipGetSymbolAddress(&pperm_, HIP_SYMBOL(g_perm2));
  hipGetSymbolAddress(&pbs_,   HIP_SYMBOL(g_bsum));
  unsigned short* mega = (unsigned short*)pmega_;
  unsigned short* qs   = (unsigned short*)pqs_;
  unsigned short* kv   = (unsigned short*)pkv_;
  unsigned short* eb1  = (unsigned short*)peb1_;
  unsigned short* eb2  = (unsigned short*)peb2_;
  unsigned short* bfA  = (unsigned short*)pbfA_;
  unsigned short* bfB  = (unsigned short*)pbfB_;
  unsigned short* bfE1 = (unsigned short*)pbfE1_;
  unsigned short* bfE2 = (unsigned short*)pbfE2_;
  unsigned short* bfW  = (unsigned short*)pbfW_;
  float* gbias = (float*)pbias_;
  int*   deg   = (int*)pdeg_;
  int*   rp    = (int*)prp_;
  int*   cur   = (int*)pcur_;
  int2*  perm2 = (int2*)pperm_;
  int*   bsum  = (int*)pbs_;

  // Weight buffers (elements): Wmega@0 (1024x256), Wqs1@262144 (512x256),
  // Wkv2@393216 (512x256), We1@524288 (256x128), We2@557056 (256x128).
  unsigned short* Wmega = bfW + 0;
  unsigned short* Wqs1  = bfW + 262144;
  unsigned short* Wkv2  = bfW + 393216;
  unsigned short* We1   = bfW + 524288;
  unsigned short* We2   = bfW + 557056;
  wconv4<<<1024, 256, 0, stream>>>(P4{{W1k, W1v, W2q, W2s}}, Wmega, 256, 1024);
  wconv4<<<512, 256, 0, stream>>>(P4{{W1q, W1s, nullptr, nullptr}}, Wqs1, 256, 512);
  wconv4<<<512, 256, 0, stream>>>(P4{{W2k, W2v, nullptr, nullptr}}, Wkv2, 256, 512);
  wconv4<<<128, 256, 0, stream>>>(P4{{W1e, nullptr, nullptr, nullptr}}, We1, 128, 256);
  wconv4<<<128, 256, 0, stream>>>(P4{{W2e, nullptr, nullptr, nullptr}}, We2, 128, 256);
  // Bias layout: mega [b1k|b1v|b2q|b2s]@0, [b1q|b1s]@1024, [b2k|b2v]@1536,
  // b1e@2048, b2e@2304.
  P10 bp{{b1k, b1v, b2q, b2s, b1q, b1s, b2k, b2v, b1e, b2e}};
  bconcat<<<10, 256, 0, stream>>>(bp, gbias);

  // Activation conversions (f32 -> bf16).
  conv_bf16<<<(int)(((long long)NT * 32 + 255) / 256), 256, 0, stream>>>(token_x, bfA, (long long)NT * 32);
  conv_bf16<<<(int)(((long long)NR * 32 + 255) / 256), 256, 0, stream>>>(row_x, bfB, (long long)NR * 32);
  conv_bf16<<<(int)(((long long)E * 16 + 255) / 256), 256, 0, stream>>>(ea1, bfE1, (long long)E * 16);
  conv_bf16<<<(int)(((long long)E * 16 + 255) / 256), 256, 0, stream>>>(ea2, bfE2, (long long)E * 16);

  const int egrid = (E + 255) / 256;

  auto csr = [&](const int* ei, int Ndst) {
    hipMemsetAsync(deg, 0, (size_t)(Ndst + 1) * sizeof(int), stream);
    hist_kernel<<<egrid, 256, 0, stream>>>(ei, deg, E);
    int B = (Ndst + 255) / 256;
    scan1<<<B, 256, 0, stream>>>(deg, rp, bsum, Ndst);
    scan2<<<1, 512, 0, stream>>>(bsum, B);
    scan3<<<B, 256, 0, stream>>>(rp, bsum, deg, cur, Ndst);
    scatter_kernel<<<egrid, 256, 0, stream>>>(ei, cur, perm2, E);
  };

  // ---------------- Projection GEMMs (round-5 structure) ----------------
  gemm_mfma<256, 1024><<<dim3((NT + 127) / 128, 8), 256, 0, stream>>>(
      bfA, Wmega, gbias + 0, mega, NT);                 // [k1|v1|q2|s2]
  gemm_mfma<256, 512><<<dim3((NR + 127) / 128, 4), 256, 0, stream>>>(
      bfB, Wqs1, gbias + 1024, qs, NR);                 // [q1|s1]
  gemm_mfma<128, 256><<<dim3((E + 127) / 128, 2), 256, 0, stream>>>(
      bfE1, We1, gbias + 2048, eb1, E);
  gemm_mfma<128, 256><<<dim3((E + 127) / 128, 2), 256, 0, stream>>>(
      bfE2, We2, gbias + 2304, eb2, E);

  // ---------------- Phase 1: t2r ----------------
  csr(ei1, NR);
  fused_attn_ln<<<(NR + 7) / 8, 256, 0, stream>>>(rp, perm2,
                                                  qs, 512, mega, 1024, eb1,
                                                  row_x, row_gamma, row_beta,
                                                  out_row, bfB, NR);

  // ---------------- Phase 2: r2t ----------------
  gemm_mfma<256, 512><<<dim3((NR + 127) / 128, 4), 256, 0, stream>>>(
      bfB, Wkv2, gbias + 1536, kv, NR);                 // [k2|v2]
  csr(ei2, NT);
  fused_attn_ln<<<(NT + 7) / 8, 256, 0, stream>>>(rp, perm2,
                                                  mega + 512, 1024, kv, 512, eb2,
                                                  token_x, token_gamma, token_beta,
                                                  out_tok, nullptr, NT);
}

// Round 10
// 676.897 us; speedup vs baseline: 1.2875x; 1.0079x over previous
//
#include <hip/hip_runtime.h>
#include <cstdint>
#include <cstddef>

#define NMAX 100000
#define EMAX 300000

typedef __bf16 bf16_t;
typedef __bf16 bf16x8 __attribute__((ext_vector_type(8)));
typedef float f32x4 __attribute__((ext_vector_type(4)));
typedef unsigned int u32;

// Static device scratch (fully rewritten every launch).
__device__ unsigned short g_mega[(size_t)NMAX * 1024];  // [k1|v1|q2|s2] bf16 (token rows)
__device__ unsigned short g_qs [(size_t)NMAX * 512];    // [q1|s1] bf16 (row rows)
__device__ unsigned short g_kv [(size_t)NMAX * 512];    // [k2|v2] bf16 (row rows)
__device__ unsigned short g_eb1[(size_t)EMAX * 256];    // e-proj phase1 bf16
__device__ unsigned short g_eb2[(size_t)EMAX * 256];    // e-proj phase2 bf16
__device__ unsigned short g_bfA[(size_t)NMAX * 256];    // token_x bf16
__device__ unsigned short g_bfB[(size_t)NMAX * 256];    // row_x bf16 -> out_row bf16
__device__ unsigned short g_bfE1[(size_t)EMAX * 128];   // edge_attr1 bf16
__device__ unsigned short g_bfE2[(size_t)EMAX * 128];   // edge_attr2 bf16
__device__ unsigned short g_bfW[589824];                // transposed bf16 weights
__device__ float g_bias[2560];                          // concat biases
__device__ int   g_deg [NMAX + 1];
__device__ int   g_rowptr[NMAX + 1];
__device__ int   g_cur [NMAX];
__device__ int2  g_perm2[EMAX];                         // (src, eid) per CSR slot
__device__ int   g_bsum[512];

struct P4  { const float* p[4]; };
struct P10 { const float* p[10]; };

__device__ __forceinline__ unsigned short f2bf(float f) {
  unsigned u = __float_as_uint(f);
  return (unsigned short)((u + 0x7fffu + ((u >> 16) & 1u)) >> 16);
}
__device__ __forceinline__ void dec8(uint4 u, float* f) {
  f[0] = __uint_as_float(u.x << 16); f[1] = __uint_as_float(u.x & 0xffff0000u);
  f[2] = __uint_as_float(u.y << 16); f[3] = __uint_as_float(u.y & 0xffff0000u);
  f[4] = __uint_as_float(u.z << 16); f[5] = __uint_as_float(u.z & 0xffff0000u);
  f[6] = __uint_as_float(u.w << 16); f[7] = __uint_as_float(u.w & 0xffff0000u);
}

// f32 -> bf16, 8 elems/thread.
__global__ __launch_bounds__(256) void conv_bf16(const float* __restrict__ in,
                                                 unsigned short* __restrict__ out,
                                                 long long n8) {
  long long i = (long long)blockIdx.x * 256 + threadIdx.x;
  if (i >= n8) return;
  const float4* p = (const float4*)(in + i * 8);
  float4 a = p[0], b = p[1];
  ushort4 lo = make_ushort4(f2bf(a.x), f2bf(a.y), f2bf(a.z), f2bf(a.w));
  ushort4 hi = make_ushort4(f2bf(b.x), f2bf(b.y), f2bf(b.z), f2bf(b.w));
  ushort4* q = (ushort4*)(out + i * 8);
  q[0] = lo; q[1] = hi;
}

// [W0|W1|W2|W3] (each [K,256] f32) -> Wt[NN,K] bf16 transposed.
__global__ __launch_bounds__(256) void wconv4(P4 Ws, unsigned short* __restrict__ Wt,
                                              int K, int NN) {
  int i = blockIdx.x * 256 + threadIdx.x;
  if (i >= NN * K) return;
  int n = i / K, k = i - n * K;
  Wt[i] = f2bf(Ws.p[n >> 8][(size_t)k * 256 + (n & 255)]);
}

// Concatenate 10 bias vectors (256 each) into g_bias.
__global__ __launch_bounds__(256) void bconcat(P10 b, float* __restrict__ out) {
  int i = blockIdx.x * 256 + threadIdx.x;
  if (i < 2560) out[i] = b.p[i >> 8][i & 255];
}

#define GLL16(gp, lp) __builtin_amdgcn_global_load_lds( \
    (const __attribute__((address_space(1))) void*)(gp), \
    (__attribute__((address_space(3))) void*)(lp), 16, 0, 0)

// C[M,NS](bf16) = bf16(A[M,K]) @ Wt^T + bias ; 128x128 tile, BK=64, 4 waves,
// 16x16x32 bf16 MFMA, global_load_lds + XOR swizzle both sides.
// 1-D swizzled grid: g = q*(8*NC) + chunk*8 + r, mt = q*8 + r. The NC
// col-chunks of one m-tile get block ids spaced exactly 8 apart -> same XCD
// (round-robin) and co-resident -> A-tile is fetched from HBM once and
// served from that XCD's L2 for the other chunks.
template <int K, int NS>
__global__ __launch_bounds__(256) void gemm_mfma(const unsigned short* __restrict__ A,
                                                 const unsigned short* __restrict__ Bt,
                                                 const float* __restrict__ bias,
                                                 unsigned short* __restrict__ C, int M) {
  constexpr int NC  = NS / 128;
  constexpr int LNC = (NC == 8) ? 3 : (NC == 4) ? 2 : 1;
  const int g = blockIdx.x;
  const int r8 = g & 7;
  const int cch = (g >> 3) & (NC - 1);
  const int q8 = g >> (3 + LNC);
  const int mt = q8 * 8 + r8;
  if (mt * 128 >= M) return;
  const int bm = mt * 128, bn = cch * 128;

  __shared__ unsigned short As[128 * 64];
  __shared__ unsigned short Bs[128 * 64];
  const int tid = threadIdx.x;
  const int lane = tid & 63, wid = tid >> 6;
  const int wrow = (wid & 1) * 64, wcol = (wid >> 1) * 64;
  const int sr = lane >> 3;
  const int slot = lane & 7;

  f32x4 acc[4][4] = {};

  for (int k0 = 0; k0 < K; k0 += 64) {
#pragma unroll
    for (int r = 0; r < 4; ++r) {
      int row = (wid * 4 + r) * 8 + sr;
      int arow = bm + row; if (arow >= M) arow = M - 1;
      int kk = k0 + ((slot ^ (row & 7)) << 3);
      GLL16(A + (size_t)arow * K + kk, (unsigned short*)As + (size_t)(wid * 4 + r) * 512);
    }
#pragma unroll
    for (int r = 0; r < 4; ++r) {
      int col = (wid * 4 + r) * 8 + sr;
      int kk = k0 + ((slot ^ (col & 7)) << 3);
      GLL16(Bt + (size_t)(bn + col) * K + kk, (unsigned short*)Bs + (size_t)(wid * 4 + r) * 512);
    }
    __syncthreads();
    const char* Ab = (const char*)As;
    const char* Bb = (const char*)Bs;
#pragma unroll
    for (int h = 0; h < 2; ++h) {
      bf16x8 af[4], bfr[4];
      int g2 = (lane >> 4) + h * 4;
#pragma unroll
      for (int fm = 0; fm < 4; ++fm) {
        int row = wrow + fm * 16 + (lane & 15);
        af[fm] = *(const bf16x8*)(Ab + row * 128 + ((g2 ^ (row & 7)) << 4));
      }
#pragma unroll
      for (int fn = 0; fn < 4; ++fn) {
        int col = wcol + fn * 16 + (lane & 15);
        bfr[fn] = *(const bf16x8*)(Bb + col * 128 + ((g2 ^ (col & 7)) << 4));
      }
#pragma unroll
      for (int fm = 0; fm < 4; ++fm)
#pragma unroll
        for (int fn = 0; fn < 4; ++fn)
          acc[fm][fn] = __builtin_amdgcn_mfma_f32_16x16x32_bf16(af[fm], bfr[fn],
                                                                acc[fm][fn], 0, 0, 0);
    }
    __syncthreads();
  }
  // Epilogue: bias + bf16 store, fn innermost for write locality.
  float bv[4];
#pragma unroll
  for (int fn = 0; fn < 4; ++fn) bv[fn] = bias[bn + wcol + fn * 16 + (lane & 15)];
#pragma unroll
  for (int fm = 0; fm < 4; ++fm) {
    int rbase = bm + wrow + fm * 16 + ((lane >> 4) << 2);
#pragma unroll
    for (int j = 0; j < 4; ++j) {
      int row = rbase + j;
      if (row < M) {
        size_t rb = (size_t)row * NS + bn + wcol + (lane & 15);
#pragma unroll
        for (int fn = 0; fn < 4; ++fn)
          C[rb + fn * 16] = f2bf(acc[fm][fn][j] + bv[fn]);
      }
    }
  }
}

// ---------------- CSR build ----------------
__global__ __launch_bounds__(256) void hist_kernel(const int* __restrict__ ei,
                                                   int* __restrict__ deg, int E) {
  int i = blockIdx.x * 256 + threadIdx.x;
  if (i < E) atomicAdd(&deg[ei[E + i]], 1);
}

__global__ __launch_bounds__(256) void scan1(const int* __restrict__ deg,
                                             int* __restrict__ rowptr,
                                             int* __restrict__ bsum, int n) {
  __shared__ int ws[4];
  int i = blockIdx.x * 256 + threadIdx.x;
  int v = (i < n) ? deg[i] : 0;
  int lane = threadIdx.x & 63, wid = threadIdx.x >> 6;
  int inc = v;
#pragma unroll
  for (int o = 1; o < 64; o <<= 1) {
    int t = __shfl_up(inc, o);
    if (lane >= o) inc += t;
  }
  if (lane == 63) ws[wid] = inc;
  __syncthreads();
  int woff = 0;
  if (wid > 0) woff += ws[0];
  if (wid > 1) woff += ws[1];
  if (wid > 2) woff += ws[2];
  if (i < n) rowptr[i] = inc - v + woff;
  if (threadIdx.x == 255) bsum[blockIdx.x] = inc + woff;
}

__global__ __launch_bounds__(512) void scan2(int* __restrict__ bsum, int B) {
  __shared__ int s[512];
  int t = threadIdx.x;
  int v = (t < B) ? bsum[t] : 0;
  s[t] = v;
  __syncthreads();
  for (int o = 1; o < 512; o <<= 1) {
    int a = (t >= o) ? s[t - o] : 0;
    __syncthreads();
    s[t] += a;
    __syncthreads();
  }
  if (t < B) bsum[t] = s[t] - v;
}

__global__ __launch_bounds__(256) void scan3(int* __restrict__ rowptr,
                                             const int* __restrict__ bsum,
                                             const int* __restrict__ deg,
                                             int* __restrict__ cur, int n) {
  int i = blockIdx.x * 256 + threadIdx.x;
  if (i < n) {
    int r = rowptr[i] + bsum[blockIdx.x];
    rowptr[i] = r;
    cur[i] = r;
    if (i == n - 1) rowptr[n] = r + deg[i];
  }
}

__global__ __launch_bounds__(256) void scatter_kernel(const int* __restrict__ ei,
                                                      int* __restrict__ cur,
                                                      int2* __restrict__ perm2, int E) {
  int i = blockIdx.x * 256 + threadIdx.x;
  if (i < E) {
    int s = ei[i];
    int d = ei[E + i];
    int pos = atomicAdd(&cur[d], 1);
    perm2[pos] = make_int2(s, i);
  }
}

// ---------------- Fused attention + skip + residual + LN (v2) ----------------
// 32 lanes per dst node (8 channels/lane, head = 8 lanes); 2 nodes/wave,
// 8 nodes/block. uint4 (16B) bf16 loads. 2-deep software-pipelined edge loop.
__global__ __launch_bounds__(256) void fused_attn_ln(
    const int* __restrict__ rowptr, const int2* __restrict__ perm2,
    const unsigned short* __restrict__ qs, int qs_stride,
    const unsigned short* __restrict__ kv, int kv_stride,
    const unsigned short* __restrict__ eb,
    const float* __restrict__ x,
    const float* __restrict__ gamma, const float* __restrict__ beta,
    float* __restrict__ out, unsigned short* __restrict__ out_bf, int N) {
  int node = blockIdx.x * 8 + (threadIdx.x >> 5);
  if (node >= N) return;
  int sub = threadIdx.x & 31;
  int c8 = sub << 3;
  uint4 qu = *(const uint4*)(qs + (size_t)node * qs_stride + c8);
  uint4 su = *(const uint4*)(qs + (size_t)node * qs_stride + 256 + c8);
  size_t base = (size_t)node * 256 + c8;
  float4 xv0 = *(const float4*)(x + base);
  float4 xv1 = *(const float4*)(x + base + 4);
  float q[8], s[8];
  dec8(qu, q); dec8(su, s);
  float acc[8] = {0.f, 0.f, 0.f, 0.f, 0.f, 0.f, 0.f, 0.f};
  float m = -1e30f, den = 0.f;
  int beg = rowptr[node], end = rowptr[node + 1];
  int2 se = (beg < end) ? perm2[beg] : make_int2(0, 0);
  uint4 ku = *(const uint4*)(kv + (size_t)se.x * kv_stride + c8);
  uint4 vu = *(const uint4*)(kv + (size_t)se.x * kv_stride + 256 + c8);
  uint4 eu = *(const uint4*)(eb + (size_t)se.y * 256 + c8);
  for (int p_ = beg; p_ < end; ++p_) {
    int2 seN = (p_ + 1 < end) ? perm2[p_ + 1] : se;
    uint4 kuN = *(const uint4*)(kv + (size_t)seN.x * kv_stride + c8);
    uint4 vuN = *(const uint4*)(kv + (size_t)seN.x * kv_stride + 256 + c8);
    uint4 euN = *(const uint4*)(eb + (size_t)seN.y * 256 + c8);
    float kf[8], vf[8], ef[8];
    dec8(ku, kf); dec8(vu, vf); dec8(eu, ef);
    float p = 0.f;
#pragma unroll
    for (int j = 0; j < 8; ++j) p += q[j] * (kf[j] + ef[j]);
    p += __shfl_xor(p, 1); p += __shfl_xor(p, 2); p += __shfl_xor(p, 4);
    p *= 0.125f;                      // SCALE = 1/sqrt(64)
    float mn = fmaxf(m, p);
    float sc = expf(m - mn);
    float w  = expf(p - mn);
    den = den * sc + w;
#pragma unroll
    for (int j = 0; j < 8; ++j) acc[j] = acc[j] * sc + w * (vf[j] + ef[j]);
    m = mn;
    ku = kuN; vu = vuN; eu = euN; se = seN;
  }
  float inv = (den > 0.f) ? 1.0f / den : 0.f;
  float val[8];
  val[0] = xv0.x + s[0] + acc[0] * inv; val[1] = xv0.y + s[1] + acc[1] * inv;
  val[2] = xv0.z + s[2] + acc[2] * inv; val[3] = xv0.w + s[3] + acc[3] * inv;
  val[4] = xv1.x + s[4] + acc[4] * inv; val[5] = xv1.y + s[5] + acc[5] * inv;
  val[6] = xv1.z + s[6] + acc[6] * inv; val[7] = xv1.w + s[7] + acc[7] * inv;
  float t = 0.f;
#pragma unroll
  for (int j = 0; j < 8; ++j) t += val[j];
#pragma unroll
  for (int o = 1; o < 32; o <<= 1) t += __shfl_xor(t, o);
  float mean = t * (1.0f / 256.0f);
  float d[8], ss = 0.f;
#pragma unroll
  for (int j = 0; j < 8; ++j) { d[j] = val[j] - mean; ss += d[j] * d[j]; }
#pragma unroll
  for (int o = 1; o < 32; o <<= 1) ss += __shfl_xor(ss, o);
  float rstd = rsqrtf(ss * (1.0f / 256.0f) + 1e-5f);
  float4 g0 = *(const float4*)(gamma + c8);
  float4 g1 = *(const float4*)(gamma + c8 + 4);
  float4 b0 = *(const float4*)(beta + c8);
  float4 b1 = *(const float4*)(beta + c8 + 4);
  float o8[8];
  o8[0] = d[0] * rstd * g0.x + b0.x; o8[1] = d[1] * rstd * g0.y + b0.y;
  o8[2] = d[2] * rstd * g0.z + b0.z; o8[3] = d[3] * rstd * g0.w + b0.w;
  o8[4] = d[4] * rstd * g1.x + b1.x; o8[5] = d[5] * rstd * g1.y + b1.y;
  o8[6] = d[6] * rstd * g1.z + b1.z; o8[7] = d[7] * rstd * g1.w + b1.w;
  *(float4*)(out + base)     = make_float4(o8[0], o8[1], o8[2], o8[3]);
  *(float4*)(out + base + 4) = make_float4(o8[4], o8[5], o8[6], o8[7]);
  if (out_bf) {
    uint4 ob;
    ob.x = (u32)f2bf(o8[0]) | ((u32)f2bf(o8[1]) << 16);
    ob.y = (u32)f2bf(o8[2]) | ((u32)f2bf(o8[3]) << 16);
    ob.z = (u32)f2bf(o8[4]) | ((u32)f2bf(o8[5]) << 16);
    ob.w = (u32)f2bf(o8[6]) | ((u32)f2bf(o8[7]) << 16);
    *(uint4*)(out_bf + base) = ob;
  }
}

extern "C" void kernel_launch(void* const* d_in, const int* in_sizes, int n_in,
                              void* d_out, int out_size, void* d_ws, size_t ws_size,
                              hipStream_t stream) {
  const float* row_x   = (const float*)d_in[0];
  const float* token_x = (const float*)d_in[1];
  const int*   ei1     = (const int*)d_in[2];    // int32 (JAX x64 disabled)
  const float* ea1     = (const float*)d_in[3];
  const int*   ei2     = (const int*)d_in[4];
  const float* ea2     = (const float*)d_in[5];

  const float* W1q = (const float*)d_in[6];  const float* b1q = (const float*)d_in[7];
  const float* W1k = (const float*)d_in[8];  const float* b1k = (const float*)d_in[9];
  const float* W1v = (const float*)d_in[10]; const float* b1v = (const float*)d_in[11];
  const float* W1e = (const float*)d_in[12]; const float* b1e = (const float*)d_in[13];
  const float* W1s = (const float*)d_in[14]; const float* b1s = (const float*)d_in[15];
  const float* W2q = (const float*)d_in[16]; const float* b2q = (const float*)d_in[17];
  const float* W2k = (const float*)d_in[18]; const float* b2k = (const float*)d_in[19];
  const float* W2v = (const float*)d_in[20]; const float* b2v = (const float*)d_in[21];
  const float* W2e = (const float*)d_in[22]; const float* b2e = (const float*)d_in[23];
  const float* W2s = (const float*)d_in[24]; const float* b2s = (const float*)d_in[25];
  const float* row_gamma   = (const float*)d_in[26];
  const float* row_beta    = (const float*)d_in[27];
  const float* token_gamma = (const float*)d_in[28];
  const float* token_beta  = (const float*)d_in[29];

  const int NR = in_sizes[0] / 256;   // 20000
  const int NT = in_sizes[1] / 256;   // 100000
  const int E  = in_sizes[2] / 2;     // 300000

  float* out_row = (float*)d_out;
  float* out_tok = (float*)d_out + (long long)NR * 256;

  void *pmega_, *pqs_, *pkv_, *peb1_, *peb2_, *pbfA_, *pbfB_, *pbfE1_, *pbfE2_,
       *pbfW_, *pbias_, *pdeg_, *prp_, *pcur_, *pperm_, *pbs_;
  hipGetSymbolAddress(&pmega_, HIP_SYMBOL(g_mega));
  hipGetSymbolAddress(&pqs_,   HIP_SYMBOL(g_qs));
  hipGetSymbolAddress(&pkv_,   HIP_SYMBOL(g_kv));
  hipGetSymbolAddress(&peb1_,  HIP_SYMBOL(g_eb1));
  hipGetSymbolAddress(&peb2_,  HIP_SYMBOL(g_eb2));
  hipGetSymbolAddress(&pbfA_,  HIP_SYMBOL(g_bfA));
  hipGetSymbolAddress(&pbfB_,  HIP_SYMBOL(g_bfB));
  hipGetSymbolAddress(&pbfE1_, HIP_SYMBOL(g_bfE1));
  hipGetSymbolAddress(&pbfE2_, HIP_SYMBOL(g_bfE2));
  hipGetSymbolAddress(&pbfW_,  HIP_SYMBOL(g_bfW));
  hipGetSymbolAddress(&pbias_, HIP_SYMBOL(g_bias));
  hipGetSymbolAddress(&pdeg_,  HIP_SYMBOL(g_deg));
  hipGetSymbolAddress(&prp_,   HIP_SYMBOL(g_rowptr));
  hipGetSymbolAddress(&pcur_,  HIP_SYMBOL(g_cur));
  hipGetSymbolAddress(&pperm_, HIP_SYMBOL(g_perm2));
  hipGetSymbolAddress(&pbs_,   HIP_SYMBOL(g_bsum));
  unsigned short* mega = (unsigned short*)pmega_;
  unsigned short* qs   = (unsigned short*)pqs_;
  unsigned short* kv   = (unsigned short*)pkv_;
  unsigned short* eb1  = (unsigned short*)peb1_;
  unsigned short* eb2  = (unsigned short*)peb2_;
  unsigned short* bfA  = (unsigned short*)pbfA_;
  unsigned short* bfB  = (unsigned short*)pbfB_;
  unsigned short* bfE1 = (unsigned short*)pbfE1_;
  unsigned short* bfE2 = (unsigned short*)pbfE2_;
  unsigned short* bfW  = (unsigned short*)pbfW_;
  float* gbias = (float*)pbias_;
  int*   deg   = (int*)pdeg_;
  int*   rp    = (int*)prp_;
  int*   cur   = (int*)pcur_;
  int2*  perm2 = (int2*)pperm_;
  int*   bsum  = (int*)pbs_;

  // Weight buffers (elements): Wmega@0 (1024x256), Wqs1@262144 (512x256),
  // Wkv2@393216 (512x256), We1@524288 (256x128), We2@557056 (256x128).
  unsigned short* Wmega = bfW + 0;
  unsigned short* Wqs1  = bfW + 262144;
  unsigned short* Wkv2  = bfW + 393216;
  unsigned short* We1   = bfW + 524288;
  unsigned short* We2   = bfW + 557056;
  wconv4<<<1024, 256, 0, stream>>>(P4{{W1k, W1v, W2q, W2s}}, Wmega, 256, 1024);
  wconv4<<<512, 256, 0, stream>>>(P4{{W1q, W1s, nullptr, nullptr}}, Wqs1, 256, 512);
  wconv4<<<512, 256, 0, stream>>>(P4{{W2k, W2v, nullptr, nullptr}}, Wkv2, 256, 512);
  wconv4<<<128, 256, 0, stream>>>(P4{{W1e, nullptr, nullptr, nullptr}}, We1, 128, 256);
  wconv4<<<128, 256, 0, stream>>>(P4{{W2e, nullptr, nullptr, nullptr}}, We2, 128, 256);
  // Bias layout: mega [b1k|b1v|b2q|b2s]@0, [b1q|b1s]@1024, [b2k|b2v]@1536,
  // b1e@2048, b2e@2304.
  P10 bp{{b1k, b1v, b2q, b2s, b1q, b1s, b2k, b2v, b1e, b2e}};
  bconcat<<<10, 256, 0, stream>>>(bp, gbias);

  // Activation conversions (f32 -> bf16).
  conv_bf16<<<(int)(((long long)NT * 32 + 255) / 256), 256, 0, stream>>>(token_x, bfA, (long long)NT * 32);
  conv_bf16<<<(int)(((long long)NR * 32 + 255) / 256), 256, 0, stream>>>(row_x, bfB, (long long)NR * 32);
  conv_bf16<<<(int)(((long long)E * 16 + 255) / 256), 256, 0, stream>>>(ea1, bfE1, (long long)E * 16);
  conv_bf16<<<(int)(((long long)E * 16 + 255) / 256), 256, 0, stream>>>(ea2, bfE2, (long long)E * 16);

  const int egrid = (E + 255) / 256;

  auto csr = [&](const int* ei, int Ndst) {
    hipMemsetAsync(deg, 0, (size_t)(Ndst + 1) * sizeof(int), stream);
    hist_kernel<<<egrid, 256, 0, stream>>>(ei, deg, E);
    int B = (Ndst + 255) / 256;
    scan1<<<B, 256, 0, stream>>>(deg, rp, bsum, Ndst);
    scan2<<<1, 512, 0, stream>>>(bsum, B);
    scan3<<<B, 256, 0, stream>>>(rp, bsum, deg, cur, Ndst);
    scatter_kernel<<<egrid, 256, 0, stream>>>(ei, cur, perm2, E);
  };

  // Swizzled 1-D grid size: ceil(nm/8)*8 * NC.
  auto swgrid = [](int M, int NC) {
    int nm = (M + 127) / 128;
    return (((nm + 7) / 8) * 8) * NC;
  };

  // ---------------- Projection GEMMs ----------------
  gemm_mfma<256, 1024><<<swgrid(NT, 8), 256, 0, stream>>>(
      bfA, Wmega, gbias + 0, mega, NT);                 // [k1|v1|q2|s2]
  gemm_mfma<256, 512><<<swgrid(NR, 4), 256, 0, stream>>>(
      bfB, Wqs1, gbias + 1024, qs, NR);                 // [q1|s1]
  gemm_mfma<128, 256><<<swgrid(E, 2), 256, 0, stream>>>(
      bfE1, We1, gbias + 2048, eb1, E);
  gemm_mfma<128, 256><<<swgrid(E, 2), 256, 0, stream>>>(
      bfE2, We2, gbias + 2304, eb2, E);

  // ---------------- Phase 1: t2r ----------------
  csr(ei1, NR);
  fused_attn_ln<<<(NR + 7) / 8, 256, 0, stream>>>(rp, perm2,
                                                  qs, 512, mega, 1024, eb1,
                                                  row_x, row_gamma, row_beta,
                                                  out_row, bfB, NR);

  // ---------------- Phase 2: r2t ----------------
  gemm_mfma<256, 512><<<swgrid(NR, 4), 256, 0, stream>>>(
      bfB, Wkv2, gbias + 1536, kv, NR);                 // [k2|v2]
  csr(ei2, NT);
  fused_attn_ln<<<(NT + 7) / 8, 256, 0, stream>>>(rp, perm2,
                                                  mega + 512, 1024, kv, 512, eb2,
                                                  token_x, token_gamma, token_beta,
                                                  out_tok, nullptr, NT);
}

// Round 11
// 668.774 us; speedup vs baseline: 1.3032x; 1.0121x over previous
//
#include <hip/hip_runtime.h>
#include <cstdint>
#include <cstddef>

#define NMAX 100000
#define EMAX 300000

typedef __bf16 bf16_t;
typedef __bf16 bf16x8 __attribute__((ext_vector_type(8)));
typedef float f32x4 __attribute__((ext_vector_type(4)));
typedef unsigned int u32;

// Static device scratch (fully rewritten every launch).
__device__ unsigned short g_mega[(size_t)NMAX * 1024];  // [k1|v1|q2|s2] bf16 (token rows)
__device__ unsigned short g_qs [(size_t)NMAX * 512];    // [q1|s1] bf16 (row rows)
__device__ unsigned short g_kv [(size_t)NMAX * 512];    // [k2|v2] bf16 (row rows)
__device__ unsigned short g_eb1[(size_t)EMAX * 256];    // e-proj phase1 bf16
__device__ unsigned short g_eb2[(size_t)EMAX * 256];    // e-proj phase2 bf16
__device__ unsigned short g_bfB[(size_t)NMAX * 256];    // out_row bf16 (fused1 -> kv2 A)
__device__ unsigned short g_bfW[589824];                // transposed bf16 weights
__device__ float g_bias[2560];                          // concat biases
__device__ int   g_deg [NMAX + 1];
__device__ int   g_rowptr[NMAX + 1];
__device__ int   g_cur [NMAX];
__device__ int2  g_perm2[EMAX];                         // (src, eid) per CSR slot
__device__ int   g_bsum[512];

struct P4  { const float* p[4]; };
struct P10 { const float* p[10]; };

__device__ __forceinline__ unsigned short f2bf(float f) {
  unsigned u = __float_as_uint(f);
  return (unsigned short)((u + 0x7fffu + ((u >> 16) & 1u)) >> 16);
}
__device__ __forceinline__ void dec8(uint4 u, float* f) {
  f[0] = __uint_as_float(u.x << 16); f[1] = __uint_as_float(u.x & 0xffff0000u);
  f[2] = __uint_as_float(u.y << 16); f[3] = __uint_as_float(u.y & 0xffff0000u);
  f[4] = __uint_as_float(u.z << 16); f[5] = __uint_as_float(u.z & 0xffff0000u);
  f[6] = __uint_as_float(u.w << 16); f[7] = __uint_as_float(u.w & 0xffff0000u);
}

// [W0|W1|W2|W3] (each [K,256] f32) -> Wt[NN,K] bf16 transposed.
__global__ __launch_bounds__(256) void wconv4(P4 Ws, unsigned short* __restrict__ Wt,
                                              int K, int NN) {
  int i = blockIdx.x * 256 + threadIdx.x;
  if (i >= NN * K) return;
  int n = i / K, k = i - n * K;
  Wt[i] = f2bf(Ws.p[n >> 8][(size_t)k * 256 + (n & 255)]);
}

// Concatenate 10 bias vectors (256 each) into g_bias.
__global__ __launch_bounds__(256) void bconcat(P10 b, float* __restrict__ out) {
  int i = blockIdx.x * 256 + threadIdx.x;
  if (i < 2560) out[i] = b.p[i >> 8][i & 255];
}

#define GLL16(gp, lp) __builtin_amdgcn_global_load_lds( \
    (const __attribute__((address_space(1))) void*)(gp), \
    (__attribute__((address_space(3))) void*)(lp), 16, 0, 0)

// C[M,NS](bf16) = bf16(A[M,K]) @ Wt^T + bias ; 128x128 tile, BK=64, 4 waves,
// 16x16x32 bf16 MFMA, XOR-swizzled LDS. A path: AF32 -> reg-staged f32 loads
// + in-reg cvt + ds_write_b128 (identical LDS layout, fuses the conv pass);
// bf16 -> global_load_lds direct. B always global_load_lds.
// 1-D XCD-swizzled grid: g = q*(8*NC) + chunk*8 + r, mt = q*8+r -> the NC
// col-chunks of one m-tile land on the SAME XCD (ids 8 apart) and share the
// A-tile via that XCD's L2 (verified r10: FETCH 202->28 MB).
template <int K, int NS, bool AF32>
__global__ __launch_bounds__(256) void gemm_mfma(const void* __restrict__ Av,
                                                 const unsigned short* __restrict__ Bt,
                                                 const float* __restrict__ bias,
                                                 unsigned short* __restrict__ C, int M) {
  constexpr int NC  = NS / 128;
  constexpr int LNC = (NC == 8) ? 3 : (NC == 4) ? 2 : 1;
  const int g = blockIdx.x;
  const int r8 = g & 7;
  const int cch = (g >> 3) & (NC - 1);
  const int q8 = g >> (3 + LNC);
  const int mt = q8 * 8 + r8;
  if (mt * 128 >= M) return;
  const int bm = mt * 128, bn = cch * 128;

  __shared__ __align__(16) unsigned short As[128 * 64];
  __shared__ __align__(16) unsigned short Bs[128 * 64];
  const int tid = threadIdx.x;
  const int lane = tid & 63, wid = tid >> 6;
  const int wrow = (wid & 1) * 64, wcol = (wid >> 1) * 64;
  const int sr = lane >> 3;
  const int slot = lane & 7;

  f32x4 acc[4][4] = {};

  for (int k0 = 0; k0 < K; k0 += 64) {
    // B staging first (async global_load_lds, stays in flight over A work).
    {
#pragma unroll
      for (int r = 0; r < 4; ++r) {
        int col = (wid * 4 + r) * 8 + sr;
        int kk = k0 + ((slot ^ (col & 7)) << 3);
        GLL16(Bt + (size_t)(bn + col) * K + kk, (unsigned short*)Bs + (size_t)(wid * 4 + r) * 512);
      }
    }
    // A staging.
    if constexpr (AF32) {
      const float* Af = (const float*)Av;
#pragma unroll
      for (int r = 0; r < 4; ++r) {
        int row = (wid * 4 + r) * 8 + sr;
        int arow = bm + row; if (arow >= M) arow = M - 1;
        int kk = k0 + ((slot ^ (row & 7)) << 3);
        const float* ap = Af + (size_t)arow * K + kk;
        float4 f0 = *(const float4*)ap;
        float4 f1 = *(const float4*)(ap + 4);
        bf16x8 a;
        a[0] = (bf16_t)f0.x; a[1] = (bf16_t)f0.y; a[2] = (bf16_t)f0.z; a[3] = (bf16_t)f0.w;
        a[4] = (bf16_t)f1.x; a[5] = (bf16_t)f1.y; a[6] = (bf16_t)f1.z; a[7] = (bf16_t)f1.w;
        *(bf16x8*)((char*)As + (size_t)row * 128 + (size_t)(slot << 4)) = a;
      }
    } else {
      const unsigned short* Af = (const unsigned short*)Av;
#pragma unroll
      for (int r = 0; r < 4; ++r) {
        int row = (wid * 4 + r) * 8 + sr;
        int arow = bm + row; if (arow >= M) arow = M - 1;
        int kk = k0 + ((slot ^ (row & 7)) << 3);
        GLL16(Af + (size_t)arow * K + kk, (unsigned short*)As + (size_t)(wid * 4 + r) * 512);
      }
    }
    __syncthreads();
    const char* Ab = (const char*)As;
    const char* Bb = (const char*)Bs;
#pragma unroll
    for (int h = 0; h < 2; ++h) {
      bf16x8 af[4], bfr[4];
      int g2 = (lane >> 4) + h * 4;
#pragma unroll
      for (int fm = 0; fm < 4; ++fm) {
        int row = wrow + fm * 16 + (lane & 15);
        af[fm] = *(const bf16x8*)(Ab + row * 128 + ((g2 ^ (row & 7)) << 4));
      }
#pragma unroll
      for (int fn = 0; fn < 4; ++fn) {
        int col = wcol + fn * 16 + (lane & 15);
        bfr[fn] = *(const bf16x8*)(Bb + col * 128 + ((g2 ^ (col & 7)) << 4));
      }
#pragma unroll
      for (int fm = 0; fm < 4; ++fm)
#pragma unroll
        for (int fn = 0; fn < 4; ++fn)
          acc[fm][fn] = __builtin_amdgcn_mfma_f32_16x16x32_bf16(af[fm], bfr[fn],
                                                                acc[fm][fn], 0, 0, 0);
    }
    __syncthreads();
  }
  // Epilogue: bias + bf16 store, fn innermost for write locality.
  float bv[4];
#pragma unroll
  for (int fn = 0; fn < 4; ++fn) bv[fn] = bias[bn + wcol + fn * 16 + (lane & 15)];
#pragma unroll
  for (int fm = 0; fm < 4; ++fm) {
    int rbase = bm + wrow + fm * 16 + ((lane >> 4) << 2);
#pragma unroll
    for (int j = 0; j < 4; ++j) {
      int row = rbase + j;
      if (row < M) {
        size_t rb = (size_t)row * NS + bn + wcol + (lane & 15);
#pragma unroll
        for (int fn = 0; fn < 4; ++fn)
          C[rb + fn * 16] = f2bf(acc[fm][fn][j] + bv[fn]);
      }
    }
  }
}

// ---------------- CSR build ----------------
__global__ __launch_bounds__(256) void hist_kernel(const int* __restrict__ ei,
                                                   int* __restrict__ deg, int E) {
  int i = blockIdx.x * 256 + threadIdx.x;
  if (i < E) atomicAdd(&deg[ei[E + i]], 1);
}

__global__ __launch_bounds__(256) void scan1(const int* __restrict__ deg,
                                             int* __restrict__ rowptr,
                                             int* __restrict__ bsum, int n) {
  __shared__ int ws[4];
  int i = blockIdx.x * 256 + threadIdx.x;
  int v = (i < n) ? deg[i] : 0;
  int lane = threadIdx.x & 63, wid = threadIdx.x >> 6;
  int inc = v;
#pragma unroll
  for (int o = 1; o < 64; o <<= 1) {
    int t = __shfl_up(inc, o);
    if (lane >= o) inc += t;
  }
  if (lane == 63) ws[wid] = inc;
  __syncthreads();
  int woff = 0;
  if (wid > 0) woff += ws[0];
  if (wid > 1) woff += ws[1];
  if (wid > 2) woff += ws[2];
  if (i < n) rowptr[i] = inc - v + woff;
  if (threadIdx.x == 255) bsum[blockIdx.x] = inc + woff;
}

__global__ __launch_bounds__(512) void scan2(int* __restrict__ bsum, int B) {
  __shared__ int s[512];
  int t = threadIdx.x;
  int v = (t < B) ? bsum[t] : 0;
  s[t] = v;
  __syncthreads();
  for (int o = 1; o < 512; o <<= 1) {
    int a = (t >= o) ? s[t - o] : 0;
    __syncthreads();
    s[t] += a;
    __syncthreads();
  }
  if (t < B) bsum[t] = s[t] - v;
}

__global__ __launch_bounds__(256) void scan3(int* __restrict__ rowptr,
                                             const int* __restrict__ bsum,
                                             const int* __restrict__ deg,
                                             int* __restrict__ cur, int n) {
  int i = blockIdx.x * 256 + threadIdx.x;
  if (i < n) {
    int r = rowptr[i] + bsum[blockIdx.x];
    rowptr[i] = r;
    cur[i] = r;
    if (i == n - 1) rowptr[n] = r + deg[i];
  }
}

__global__ __launch_bounds__(256) void scatter_kernel(const int* __restrict__ ei,
                                                      int* __restrict__ cur,
                                                      int2* __restrict__ perm2, int E) {
  int i = blockIdx.x * 256 + threadIdx.x;
  if (i < E) {
    int s = ei[i];
    int d = ei[E + i];
    int pos = atomicAdd(&cur[d], 1);
    perm2[pos] = make_int2(s, i);
  }
}

// ---------------- Fused attention + skip + residual + LN (v2) ----------------
// 32 lanes per dst node (8 channels/lane, head = 8 lanes); 2 nodes/wave,
// 8 nodes/block. uint4 (16B) bf16 loads. 2-deep software-pipelined edge loop.
__global__ __launch_bounds__(256) void fused_attn_ln(
    const int* __restrict__ rowptr, const int2* __restrict__ perm2,
    const unsigned short* __restrict__ qs, int qs_stride,
    const unsigned short* __restrict__ kv, int kv_stride,
    const unsigned short* __restrict__ eb,
    const float* __restrict__ x,
    const float* __restrict__ gamma, const float* __restrict__ beta,
    float* __restrict__ out, unsigned short* __restrict__ out_bf, int N) {
  int node = blockIdx.x * 8 + (threadIdx.x >> 5);
  if (node >= N) return;
  int sub = threadIdx.x & 31;
  int c8 = sub << 3;
  uint4 qu = *(const uint4*)(qs + (size_t)node * qs_stride + c8);
  uint4 su = *(const uint4*)(qs + (size_t)node * qs_stride + 256 + c8);
  size_t base = (size_t)node * 256 + c8;
  float4 xv0 = *(const float4*)(x + base);
  float4 xv1 = *(const float4*)(x + base + 4);
  float q[8], s[8];
  dec8(qu, q); dec8(su, s);
  float acc[8] = {0.f, 0.f, 0.f, 0.f, 0.f, 0.f, 0.f, 0.f};
  float m = -1e30f, den = 0.f;
  int beg = rowptr[node], end = rowptr[node + 1];
  int2 se = (beg < end) ? perm2[beg] : make_int2(0, 0);
  uint4 ku = *(const uint4*)(kv + (size_t)se.x * kv_stride + c8);
  uint4 vu = *(const uint4*)(kv + (size_t)se.x * kv_stride + 256 + c8);
  uint4 eu = *(const uint4*)(eb + (size_t)se.y * 256 + c8);
  for (int p_ = beg; p_ < end; ++p_) {
    int2 seN = (p_ + 1 < end) ? perm2[p_ + 1] : se;
    uint4 kuN = *(const uint4*)(kv + (size_t)seN.x * kv_stride + c8);
    uint4 vuN = *(const uint4*)(kv + (size_t)seN.x * kv_stride + 256 + c8);
    uint4 euN = *(const uint4*)(eb + (size_t)seN.y * 256 + c8);
    float kf[8], vf[8], ef[8];
    dec8(ku, kf); dec8(vu, vf); dec8(eu, ef);
    float p = 0.f;
#pragma unroll
    for (int j = 0; j < 8; ++j) p += q[j] * (kf[j] + ef[j]);
    p += __shfl_xor(p, 1); p += __shfl_xor(p, 2); p += __shfl_xor(p, 4);
    p *= 0.125f;                      // SCALE = 1/sqrt(64)
    float mn = fmaxf(m, p);
    float sc = expf(m - mn);
    float w  = expf(p - mn);
    den = den * sc + w;
#pragma unroll
    for (int j = 0; j < 8; ++j) acc[j] = acc[j] * sc + w * (vf[j] + ef[j]);
    m = mn;
    ku = kuN; vu = vuN; eu = euN; se = seN;
  }
  float inv = (den > 0.f) ? 1.0f / den : 0.f;
  float val[8];
  val[0] = xv0.x + s[0] + acc[0] * inv; val[1] = xv0.y + s[1] + acc[1] * inv;
  val[2] = xv0.z + s[2] + acc[2] * inv; val[3] = xv0.w + s[3] + acc[3] * inv;
  val[4] = xv1.x + s[4] + acc[4] * inv; val[5] = xv1.y + s[5] + acc[5] * inv;
  val[6] = xv1.z + s[6] + acc[6] * inv; val[7] = xv1.w + s[7] + acc[7] * inv;
  float t = 0.f;
#pragma unroll
  for (int j = 0; j < 8; ++j) t += val[j];
#pragma unroll
  for (int o = 1; o < 32; o <<= 1) t += __shfl_xor(t, o);
  float mean = t * (1.0f / 256.0f);
  float d[8], ss = 0.f;
#pragma unroll
  for (int j = 0; j < 8; ++j) { d[j] = val[j] - mean; ss += d[j] * d[j]; }
#pragma unroll
  for (int o = 1; o < 32; o <<= 1) ss += __shfl_xor(ss, o);
  float rstd = rsqrtf(ss * (1.0f / 256.0f) + 1e-5f);
  float4 g0 = *(const float4*)(gamma + c8);
  float4 g1 = *(const float4*)(gamma + c8 + 4);
  float4 b0 = *(const float4*)(beta + c8);
  float4 b1 = *(const float4*)(beta + c8 + 4);
  float o8[8];
  o8[0] = d[0] * rstd * g0.x + b0.x; o8[1] = d[1] * rstd * g0.y + b0.y;
  o8[2] = d[2] * rstd * g0.z + b0.z; o8[3] = d[3] * rstd * g0.w + b0.w;
  o8[4] = d[4] * rstd * g1.x + b1.x; o8[5] = d[5] * rstd * g1.y + b1.y;
  o8[6] = d[6] * rstd * g1.z + b1.z; o8[7] = d[7] * rstd * g1.w + b1.w;
  *(float4*)(out + base)     = make_float4(o8[0], o8[1], o8[2], o8[3]);
  *(float4*)(out + base + 4) = make_float4(o8[4], o8[5], o8[6], o8[7]);
  if (out_bf) {
    uint4 ob;
    ob.x = (u32)f2bf(o8[0]) | ((u32)f2bf(o8[1]) << 16);
    ob.y = (u32)f2bf(o8[2]) | ((u32)f2bf(o8[3]) << 16);
    ob.z = (u32)f2bf(o8[4]) | ((u32)f2bf(o8[5]) << 16);
    ob.w = (u32)f2bf(o8[6]) | ((u32)f2bf(o8[7]) << 16);
    *(uint4*)(out_bf + base) = ob;
  }
}

extern "C" void kernel_launch(void* const* d_in, const int* in_sizes, int n_in,
                              void* d_out, int out_size, void* d_ws, size_t ws_size,
                              hipStream_t stream) {
  const float* row_x   = (const float*)d_in[0];
  const float* token_x = (const float*)d_in[1];
  const int*   ei1     = (const int*)d_in[2];    // int32 (JAX x64 disabled)
  const float* ea1     = (const float*)d_in[3];
  const int*   ei2     = (const int*)d_in[4];
  const float* ea2     = (const float*)d_in[5];

  const float* W1q = (const float*)d_in[6];  const float* b1q = (const float*)d_in[7];
  const float* W1k = (const float*)d_in[8];  const float* b1k = (const float*)d_in[9];
  const float* W1v = (const float*)d_in[10]; const float* b1v = (const float*)d_in[11];
  const float* W1e = (const float*)d_in[12]; const float* b1e = (const float*)d_in[13];
  const float* W1s = (const float*)d_in[14]; const float* b1s = (const float*)d_in[15];
  const float* W2q = (const float*)d_in[16]; const float* b2q = (const float*)d_in[17];
  const float* W2k = (const float*)d_in[18]; const float* b2k = (const float*)d_in[19];
  const float* W2v = (const float*)d_in[20]; const float* b2v = (const float*)d_in[21];
  const float* W2e = (const float*)d_in[22]; const float* b2e = (const float*)d_in[23];
  const float* W2s = (const float*)d_in[24]; const float* b2s = (const float*)d_in[25];
  const float* row_gamma   = (const float*)d_in[26];
  const float* row_beta    = (const float*)d_in[27];
  const float* token_gamma = (const float*)d_in[28];
  const float* token_beta  = (const float*)d_in[29];

  const int NR = in_sizes[0] / 256;   // 20000
  const int NT = in_sizes[1] / 256;   // 100000
  const int E  = in_sizes[2] / 2;     // 300000

  float* out_row = (float*)d_out;
  float* out_tok = (float*)d_out + (long long)NR * 256;

  void *pmega_, *pqs_, *pkv_, *peb1_, *peb2_, *pbfB_,
       *pbfW_, *pbias_, *pdeg_, *prp_, *pcur_, *pperm_, *pbs_;
  hipGetSymbolAddress(&pmega_, HIP_SYMBOL(g_mega));
  hipGetSymbolAddress(&pqs_,   HIP_SYMBOL(g_qs));
  hipGetSymbolAddress(&pkv_,   HIP_SYMBOL(g_kv));
  hipGetSymbolAddress(&peb1_,  HIP_SYMBOL(g_eb1));
  hipGetSymbolAddress(&peb2_,  HIP_SYMBOL(g_eb2));
  hipGetSymbolAddress(&pbfB_,  HIP_SYMBOL(g_bfB));
  hipGetSymbolAddress(&pbfW_,  HIP_SYMBOL(g_bfW));
  hipGetSymbolAddress(&pbias_, HIP_SYMBOL(g_bias));
  hipGetSymbolAddress(&pdeg_,  HIP_SYMBOL(g_deg));
  hipGetSymbolAddress(&prp_,   HIP_SYMBOL(g_rowptr));
  hipGetSymbolAddress(&pcur_,  HIP_SYMBOL(g_cur));
  hipGetSymbolAddress(&pperm_, HIP_SYMBOL(g_perm2));
  hipGetSymbolAddress(&pbs_,   HIP_SYMBOL(g_bsum));
  unsigned short* mega = (unsigned short*)pmega_;
  unsigned short* qs   = (unsigned short*)pqs_;
  unsigned short* kv   = (unsigned short*)pkv_;
  unsigned short* eb1  = (unsigned short*)peb1_;
  unsigned short* eb2  = (unsigned short*)peb2_;
  unsigned short* bfB  = (unsigned short*)pbfB_;
  unsigned short* bfW  = (unsigned short*)pbfW_;
  float* gbias = (float*)pbias_;
  int*   deg   = (int*)pdeg_;
  int*   rp    = (int*)prp_;
  int*   cur   = (int*)pcur_;
  int2*  perm2 = (int2*)pperm_;
  int*   bsum  = (int*)pbs_;

  // Weight buffers (elements): Wmega@0 (1024x256), Wqs1@262144 (512x256),
  // Wkv2@393216 (512x256), We1@524288 (256x128), We2@557056 (256x128).
  unsigned short* Wmega = bfW + 0;
  unsigned short* Wqs1  = bfW + 262144;
  unsigned short* Wkv2  = bfW + 393216;
  unsigned short* We1   = bfW + 524288;
  unsigned short* We2   = bfW + 557056;
  wconv4<<<1024, 256, 0, stream>>>(P4{{W1k, W1v, W2q, W2s}}, Wmega, 256, 1024);
  wconv4<<<512, 256, 0, stream>>>(P4{{W1q, W1s, nullptr, nullptr}}, Wqs1, 256, 512);
  wconv4<<<512, 256, 0, stream>>>(P4{{W2k, W2v, nullptr, nullptr}}, Wkv2, 256, 512);
  wconv4<<<128, 256, 0, stream>>>(P4{{W1e, nullptr, nullptr, nullptr}}, We1, 128, 256);
  wconv4<<<128, 256, 0, stream>>>(P4{{W2e, nullptr, nullptr, nullptr}}, We2, 128, 256);
  // Bias layout: mega [b1k|b1v|b2q|b2s]@0, [b1q|b1s]@1024, [b2k|b2v]@1536,
  // b1e@2048, b2e@2304.
  P10 bp{{b1k, b1v, b2q, b2s, b1q, b1s, b2k, b2v, b1e, b2e}};
  bconcat<<<10, 256, 0, stream>>>(bp, gbias);

  const int egrid = (E + 255) / 256;

  auto csr = [&](const int* ei, int Ndst) {
    hipMemsetAsync(deg, 0, (size_t)(Ndst + 1) * sizeof(int), stream);
    hist_kernel<<<egrid, 256, 0, stream>>>(ei, deg, E);
    int B = (Ndst + 255) / 256;
    scan1<<<B, 256, 0, stream>>>(deg, rp, bsum, Ndst);
    scan2<<<1, 512, 0, stream>>>(bsum, B);
    scan3<<<B, 256, 0, stream>>>(rp, bsum, deg, cur, Ndst);
    scatter_kernel<<<egrid, 256, 0, stream>>>(ei, cur, perm2, E);
  };

  // Swizzled 1-D grid size: ceil(nm/8)*8 * NC.
  auto swgrid = [](int M, int NC) {
    int nm = (M + 127) / 128;
    return (((nm + 7) / 8) * 8) * NC;
  };

  // ---------------- Projection GEMMs (conv fused into A-staging) ----------------
  gemm_mfma<256, 1024, true><<<swgrid(NT, 8), 256, 0, stream>>>(
      token_x, Wmega, gbias + 0, mega, NT);             // [k1|v1|q2|s2]
  gemm_mfma<256, 512, true><<<swgrid(NR, 4), 256, 0, stream>>>(
      row_x, Wqs1, gbias + 1024, qs, NR);               // [q1|s1]
  gemm_mfma<128, 256, true><<<swgrid(E, 2), 256, 0, stream>>>(
      ea1, We1, gbias + 2048, eb1, E);
  gemm_mfma<128, 256, true><<<swgrid(E, 2), 256, 0, stream>>>(
      ea2, We2, gbias + 2304, eb2, E);

  // ---------------- Phase 1: t2r ----------------
  csr(ei1, NR);
  fused_attn_ln<<<(NR + 7) / 8, 256, 0, stream>>>(rp, perm2,
                                                  qs, 512, mega, 1024, eb1,
                                                  row_x, row_gamma, row_beta,
                                                  out_row, bfB, NR);

  // ---------------- Phase 2: r2t ----------------
  gemm_mfma<256, 512, false><<<swgrid(NR, 4), 256, 0, stream>>>(
      bfB, Wkv2, gbias + 1536, kv, NR);                 // [k2|v2]
  csr(ei2, NT);
  fused_attn_ln<<<(NT + 7) / 8, 256, 0, stream>>>(rp, perm2,
                                                  mega + 512, 1024, kv, 512, eb2,
                                                  token_x, token_gamma, token_beta,
                                                  out_tok, nullptr, NT);
}

// Round 12
// 653.073 us; speedup vs baseline: 1.3345x; 1.0240x over previous
//
#include <hip/hip_runtime.h>
#include <cstdint>
#include <cstddef>

#define NMAX 100000
#define EMAX 300000

typedef __bf16 bf16_t;
typedef __bf16 bf16x8 __attribute__((ext_vector_type(8)));
typedef float f32x4 __attribute__((ext_vector_type(4)));
typedef unsigned int u32;

// Static device scratch (fully rewritten every launch).
__device__ unsigned short g_mega[(size_t)NMAX * 1024];  // [k1|v1|q2|s2] bf16 (token rows)
__device__ unsigned short g_qs [(size_t)NMAX * 512];    // [q1|s1] bf16 (row rows)
__device__ unsigned short g_kv [(size_t)NMAX * 512];    // [k2|v2] bf16 (row rows)
__device__ unsigned short g_eb1[(size_t)EMAX * 256];    // e-proj phase1 bf16
__device__ unsigned short g_eb2[(size_t)EMAX * 256];    // e-proj phase2 bf16
__device__ unsigned short g_bfA[(size_t)NMAX * 256];    // token_x bf16 (mega A)
__device__ unsigned short g_bfB[(size_t)NMAX * 256];    // out_row bf16 (fused1 -> kv2 A)
__device__ unsigned short g_bfW[589824];                // transposed bf16 weights
__device__ float g_bias[2560];                          // concat biases
__device__ int   g_deg [NMAX + 1];
__device__ int   g_rowptr[NMAX + 1];
__device__ int   g_cur [NMAX];
__device__ int2  g_perm2[EMAX];                         // (src, eid) per CSR slot
__device__ int   g_bsum[512];

struct P4  { const float* p[4]; };
struct P10 { const float* p[10]; };

__device__ __forceinline__ unsigned short f2bf(float f) {
  unsigned u = __float_as_uint(f);
  return (unsigned short)((u + 0x7fffu + ((u >> 16) & 1u)) >> 16);
}
__device__ __forceinline__ void dec8(uint4 u, float* f) {
  f[0] = __uint_as_float(u.x << 16); f[1] = __uint_as_float(u.x & 0xffff0000u);
  f[2] = __uint_as_float(u.y << 16); f[3] = __uint_as_float(u.y & 0xffff0000u);
  f[4] = __uint_as_float(u.z << 16); f[5] = __uint_as_float(u.z & 0xffff0000u);
  f[6] = __uint_as_float(u.w << 16); f[7] = __uint_as_float(u.w & 0xffff0000u);
}

// f32 -> bf16, 8 elems/thread.
__global__ __launch_bounds__(256) void conv_bf16(const float* __restrict__ in,
                                                 unsigned short* __restrict__ out,
                                                 long long n8) {
  long long i = (long long)blockIdx.x * 256 + threadIdx.x;
  if (i >= n8) return;
  const float4* p = (const float4*)(in + i * 8);
  float4 a = p[0], b = p[1];
  ushort4 lo = make_ushort4(f2bf(a.x), f2bf(a.y), f2bf(a.z), f2bf(a.w));
  ushort4 hi = make_ushort4(f2bf(b.x), f2bf(b.y), f2bf(b.z), f2bf(b.w));
  ushort4* q = (ushort4*)(out + i * 8);
  q[0] = lo; q[1] = hi;
}

// [W0|W1|W2|W3] (each [K,256] f32) -> Wt[NN,K] bf16 transposed.
__global__ __launch_bounds__(256) void wconv4(P4 Ws, unsigned short* __restrict__ Wt,
                                              int K, int NN) {
  int i = blockIdx.x * 256 + threadIdx.x;
  if (i >= NN * K) return;
  int n = i / K, k = i - n * K;
  Wt[i] = f2bf(Ws.p[n >> 8][(size_t)k * 256 + (n & 255)]);
}

// Concatenate 10 bias vectors (256 each) into g_bias.
__global__ __launch_bounds__(256) void bconcat(P10 b, float* __restrict__ out) {
  int i = blockIdx.x * 256 + threadIdx.x;
  if (i < 2560) out[i] = b.p[i >> 8][i & 255];
}

#define GLL16(gp, lp) __builtin_amdgcn_global_load_lds( \
    (const __attribute__((address_space(1))) void*)(gp), \
    (__attribute__((address_space(3))) void*)(lp), 16, 0, 0)

// C[M,NS](bf16) = bf16(A[M,K]) @ Wt^T + bias ; 128x128 tile, BK=64, 4 waves,
// 16x16x32 bf16 MFMA, XOR-swizzled LDS. A path: AF32 -> reg-staged f32 loads
// + in-reg cvt + ds_write_b128 (fuses the conv pass; measured WIN for K=128,
// LOSS for K=256 mega -> mega uses bf16 path); bf16 -> global_load_lds.
// B always global_load_lds.
// 1-D XCD-swizzled grid: the NC col-chunks of one m-tile land on the SAME
// XCD (ids 8 apart) and share the A-tile via its L2 (r10: FETCH 202->28 MB).
template <int K, int NS, bool AF32>
__global__ __launch_bounds__(256) void gemm_mfma(const void* __restrict__ Av,
                                                 const unsigned short* __restrict__ Bt,
                                                 const float* __restrict__ bias,
                                                 unsigned short* __restrict__ C, int M) {
  constexpr int NC  = NS / 128;
  constexpr int LNC = (NC == 8) ? 3 : (NC == 4) ? 2 : 1;
  const int g = blockIdx.x;
  const int r8 = g & 7;
  const int cch = (g >> 3) & (NC - 1);
  const int q8 = g >> (3 + LNC);
  const int mt = q8 * 8 + r8;
  if (mt * 128 >= M) return;
  const int bm = mt * 128, bn = cch * 128;

  __shared__ __align__(16) unsigned short As[128 * 64];
  __shared__ __align__(16) unsigned short Bs[128 * 64];
  const int tid = threadIdx.x;
  const int lane = tid & 63, wid = tid >> 6;
  const int wrow = (wid & 1) * 64, wcol = (wid >> 1) * 64;
  const int sr = lane >> 3;
  const int slot = lane & 7;

  f32x4 acc[4][4] = {};

  for (int k0 = 0; k0 < K; k0 += 64) {
    // B staging first (async global_load_lds, stays in flight over A work).
    {
#pragma unroll
      for (int r = 0; r < 4; ++r) {
        int col = (wid * 4 + r) * 8 + sr;
        int kk = k0 + ((slot ^ (col & 7)) << 3);
        GLL16(Bt + (size_t)(bn + col) * K + kk, (unsigned short*)Bs + (size_t)(wid * 4 + r) * 512);
      }
    }
    // A staging.
    if constexpr (AF32) {
      const float* Af = (const float*)Av;
#pragma unroll
      for (int r = 0; r < 4; ++r) {
        int row = (wid * 4 + r) * 8 + sr;
        int arow = bm + row; if (arow >= M) arow = M - 1;
        int kk = k0 + ((slot ^ (row & 7)) << 3);
        const float* ap = Af + (size_t)arow * K + kk;
        float4 f0 = *(const float4*)ap;
        float4 f1 = *(const float4*)(ap + 4);
        bf16x8 a;
        a[0] = (bf16_t)f0.x; a[1] = (bf16_t)f0.y; a[2] = (bf16_t)f0.z; a[3] = (bf16_t)f0.w;
        a[4] = (bf16_t)f1.x; a[5] = (bf16_t)f1.y; a[6] = (bf16_t)f1.z; a[7] = (bf16_t)f1.w;
        *(bf16x8*)((char*)As + (size_t)row * 128 + (size_t)(slot << 4)) = a;
      }
    } else {
      const unsigned short* Af = (const unsigned short*)Av;
#pragma unroll
      for (int r = 0; r < 4; ++r) {
        int row = (wid * 4 + r) * 8 + sr;
        int arow = bm + row; if (arow >= M) arow = M - 1;
        int kk = k0 + ((slot ^ (row & 7)) << 3);
        GLL16(Af + (size_t)arow * K + kk, (unsigned short*)As + (size_t)(wid * 4 + r) * 512);
      }
    }
    __syncthreads();
    const char* Ab = (const char*)As;
    const char* Bb = (const char*)Bs;
#pragma unroll
    for (int h = 0; h < 2; ++h) {
      bf16x8 af[4], bfr[4];
      int g2 = (lane >> 4) + h * 4;
#pragma unroll
      for (int fm = 0; fm < 4; ++fm) {
        int row = wrow + fm * 16 + (lane & 15);
        af[fm] = *(const bf16x8*)(Ab + row * 128 + ((g2 ^ (row & 7)) << 4));
      }
#pragma unroll
      for (int fn = 0; fn < 4; ++fn) {
        int col = wcol + fn * 16 + (lane & 15);
        bfr[fn] = *(const bf16x8*)(Bb + col * 128 + ((g2 ^ (col & 7)) << 4));
      }
#pragma unroll
      for (int fm = 0; fm < 4; ++fm)
#pragma unroll
        for (int fn = 0; fn < 4; ++fn)
          acc[fm][fn] = __builtin_amdgcn_mfma_f32_16x16x32_bf16(af[fm], bfr[fn],
                                                                acc[fm][fn], 0, 0, 0);
    }
    __syncthreads();
  }
  // Epilogue: bias + bf16 store, fn innermost for write locality.
  float bv[4];
#pragma unroll
  for (int fn = 0; fn < 4; ++fn) bv[fn] = bias[bn + wcol + fn * 16 + (lane & 15)];
#pragma unroll
  for (int fm = 0; fm < 4; ++fm) {
    int rbase = bm + wrow + fm * 16 + ((lane >> 4) << 2);
#pragma unroll
    for (int j = 0; j < 4; ++j) {
      int row = rbase + j;
      if (row < M) {
        size_t rb = (size_t)row * NS + bn + wcol + (lane & 15);
#pragma unroll
        for (int fn = 0; fn < 4; ++fn)
          C[rb + fn * 16] = f2bf(acc[fm][fn][j] + bv[fn]);
      }
    }
  }
}

// ---------------- CSR build ----------------
__global__ __launch_bounds__(256) void hist_kernel(const int* __restrict__ ei,
                                                   int* __restrict__ deg, int E) {
  int i = blockIdx.x * 256 + threadIdx.x;
  if (i < E) atomicAdd(&deg[ei[E + i]], 1);
}

__global__ __launch_bounds__(256) void scan1(const int* __restrict__ deg,
                                             int* __restrict__ rowptr,
                                             int* __restrict__ bsum, int n) {
  __shared__ int ws[4];
  int i = blockIdx.x * 256 + threadIdx.x;
  int v = (i < n) ? deg[i] : 0;
  int lane = threadIdx.x & 63, wid = threadIdx.x >> 6;
  int inc = v;
#pragma unroll
  for (int o = 1; o < 64; o <<= 1) {
    int t = __shfl_up(inc, o);
    if (lane >= o) inc += t;
  }
  if (lane == 63) ws[wid] = inc;
  __syncthreads();
  int woff = 0;
  if (wid > 0) woff += ws[0];
  if (wid > 1) woff += ws[1];
  if (wid > 2) woff += ws[2];
  if (i < n) rowptr[i] = inc - v + woff;
  if (threadIdx.x == 255) bsum[blockIdx.x] = inc + woff;
}

__global__ __launch_bounds__(512) void scan2(int* __restrict__ bsum, int B) {
  __shared__ int s[512];
  int t = threadIdx.x;
  int v = (t < B) ? bsum[t] : 0;
  s[t] = v;
  __syncthreads();
  for (int o = 1; o < 512; o <<= 1) {
    int a = (t >= o) ? s[t - o] : 0;
    __syncthreads();
    s[t] += a;
    __syncthreads();
  }
  if (t < B) bsum[t] = s[t] - v;
}

__global__ __launch_bounds__(256) void scan3(int* __restrict__ rowptr,
                                             const int* __restrict__ bsum,
                                             const int* __restrict__ deg,
                                             int* __restrict__ cur, int n) {
  int i = blockIdx.x * 256 + threadIdx.x;
  if (i < n) {
    int r = rowptr[i] + bsum[blockIdx.x];
    rowptr[i] = r;
    cur[i] = r;
    if (i == n - 1) rowptr[n] = r + deg[i];
  }
}

__global__ __launch_bounds__(256) void scatter_kernel(const int* __restrict__ ei,
                                                      int* __restrict__ cur,
                                                      int2* __restrict__ perm2, int E) {
  int i = blockIdx.x * 256 + threadIdx.x;
  if (i < E) {
    int s = ei[i];
    int d = ei[E + i];
    int pos = atomicAdd(&cur[d], 1);
    perm2[pos] = make_int2(s, i);
  }
}

// ---------------- Fused attention + skip + residual + LN (v2) ----------------
// 32 lanes per dst node (8 channels/lane, head = 8 lanes); 2 nodes/wave,
// 8 nodes/block. uint4 (16B) bf16 loads. 2-deep software-pipelined edge loop.
__global__ __launch_bounds__(256) void fused_attn_ln(
    const int* __restrict__ rowptr, const int2* __restrict__ perm2,
    const unsigned short* __restrict__ qs, int qs_stride,
    const unsigned short* __restrict__ kv, int kv_stride,
    const unsigned short* __restrict__ eb,
    const float* __restrict__ x,
    const float* __restrict__ gamma, const float* __restrict__ beta,
    float* __restrict__ out, unsigned short* __restrict__ out_bf, int N) {
  int node = blockIdx.x * 8 + (threadIdx.x >> 5);
  if (node >= N) return;
  int sub = threadIdx.x & 31;
  int c8 = sub << 3;
  uint4 qu = *(const uint4*)(qs + (size_t)node * qs_stride + c8);
  uint4 su = *(const uint4*)(qs + (size_t)node * qs_stride + 256 + c8);
  size_t base = (size_t)node * 256 + c8;
  float4 xv0 = *(const float4*)(x + base);
  float4 xv1 = *(const float4*)(x + base + 4);
  float q[8], s[8];
  dec8(qu, q); dec8(su, s);
  float acc[8] = {0.f, 0.f, 0.f, 0.f, 0.f, 0.f, 0.f, 0.f};
  float m = -1e30f, den = 0.f;
  int beg = rowptr[node], end = rowptr[node + 1];
  int2 se = (beg < end) ? perm2[beg] : make_int2(0, 0);
  uint4 ku = *(const uint4*)(kv + (size_t)se.x * kv_stride + c8);
  uint4 vu = *(const uint4*)(kv + (size_t)se.x * kv_stride + 256 + c8);
  uint4 eu = *(const uint4*)(eb + (size_t)se.y * 256 + c8);
  for (int p_ = beg; p_ < end; ++p_) {
    int2 seN = (p_ + 1 < end) ? perm2[p_ + 1] : se;
    uint4 kuN = *(const uint4*)(kv + (size_t)seN.x * kv_stride + c8);
    uint4 vuN = *(const uint4*)(kv + (size_t)seN.x * kv_stride + 256 + c8);
    uint4 euN = *(const uint4*)(eb + (size_t)seN.y * 256 + c8);
    float kf[8], vf[8], ef[8];
    dec8(ku, kf); dec8(vu, vf); dec8(eu, ef);
    float p = 0.f;
#pragma unroll
    for (int j = 0; j < 8; ++j) p += q[j] * (kf[j] + ef[j]);
    p += __shfl_xor(p, 1); p += __shfl_xor(p, 2); p += __shfl_xor(p, 4);
    p *= 0.125f;                      // SCALE = 1/sqrt(64)
    float mn = fmaxf(m, p);
    float sc = expf(m - mn);
    float w  = expf(p - mn);
    den = den * sc + w;
#pragma unroll
    for (int j = 0; j < 8; ++j) acc[j] = acc[j] * sc + w * (vf[j] + ef[j]);
    m = mn;
    ku = kuN; vu = vuN; eu = euN; se = seN;
  }
  float inv = (den > 0.f) ? 1.0f / den : 0.f;
  float val[8];
  val[0] = xv0.x + s[0] + acc[0] * inv; val[1] = xv0.y + s[1] + acc[1] * inv;
  val[2] = xv0.z + s[2] + acc[2] * inv; val[3] = xv0.w + s[3] + acc[3] * inv;
  val[4] = xv1.x + s[4] + acc[4] * inv; val[5] = xv1.y + s[5] + acc[5] * inv;
  val[6] = xv1.z + s[6] + acc[6] * inv; val[7] = xv1.w + s[7] + acc[7] * inv;
  float t = 0.f;
#pragma unroll
  for (int j = 0; j < 8; ++j) t += val[j];
#pragma unroll
  for (int o = 1; o < 32; o <<= 1) t += __shfl_xor(t, o);
  float mean = t * (1.0f / 256.0f);
  float d[8], ss = 0.f;
#pragma unroll
  for (int j = 0; j < 8; ++j) { d[j] = val[j] - mean; ss += d[j] * d[j]; }
#pragma unroll
  for (int o = 1; o < 32; o <<= 1) ss += __shfl_xor(ss, o);
  float rstd = rsqrtf(ss * (1.0f / 256.0f) + 1e-5f);
  float4 g0 = *(const float4*)(gamma + c8);
  float4 g1 = *(const float4*)(gamma + c8 + 4);
  float4 b0 = *(const float4*)(beta + c8);
  float4 b1 = *(const float4*)(beta + c8 + 4);
  float o8[8];
  o8[0] = d[0] * rstd * g0.x + b0.x; o8[1] = d[1] * rstd * g0.y + b0.y;
  o8[2] = d[2] * rstd * g0.z + b0.z; o8[3] = d[3] * rstd * g0.w + b0.w;
  o8[4] = d[4] * rstd * g1.x + b1.x; o8[5] = d[5] * rstd * g1.y + b1.y;
  o8[6] = d[6] * rstd * g1.z + b1.z; o8[7] = d[7] * rstd * g1.w + b1.w;
  *(float4*)(out + base)     = make_float4(o8[0], o8[1], o8[2], o8[3]);
  *(float4*)(out + base + 4) = make_float4(o8[4], o8[5], o8[6], o8[7]);
  if (out_bf) {
    uint4 ob;
    ob.x = (u32)f2bf(o8[0]) | ((u32)f2bf(o8[1]) << 16);
    ob.y = (u32)f2bf(o8[2]) | ((u32)f2bf(o8[3]) << 16);
    ob.z = (u32)f2bf(o8[4]) | ((u32)f2bf(o8[5]) << 16);
    ob.w = (u32)f2bf(o8[6]) | ((u32)f2bf(o8[7]) << 16);
    *(uint4*)(out_bf + base) = ob;
  }
}

extern "C" void kernel_launch(void* const* d_in, const int* in_sizes, int n_in,
                              void* d_out, int out_size, void* d_ws, size_t ws_size,
                              hipStream_t stream) {
  const float* row_x   = (const float*)d_in[0];
  const float* token_x = (const float*)d_in[1];
  const int*   ei1     = (const int*)d_in[2];    // int32 (JAX x64 disabled)
  const float* ea1     = (const float*)d_in[3];
  const int*   ei2     = (const int*)d_in[4];
  const float* ea2     = (const float*)d_in[5];

  const float* W1q = (const float*)d_in[6];  const float* b1q = (const float*)d_in[7];
  const float* W1k = (const float*)d_in[8];  const float* b1k = (const float*)d_in[9];
  const float* W1v = (const float*)d_in[10]; const float* b1v = (const float*)d_in[11];
  const float* W1e = (const float*)d_in[12]; const float* b1e = (const float*)d_in[13];
  const float* W1s = (const float*)d_in[14]; const float* b1s = (const float*)d_in[15];
  const float* W2q = (const float*)d_in[16]; const float* b2q = (const float*)d_in[17];
  const float* W2k = (const float*)d_in[18]; const float* b2k = (const float*)d_in[19];
  const float* W2v = (const float*)d_in[20]; const float* b2v = (const float*)d_in[21];
  const float* W2e = (const float*)d_in[22]; const float* b2e = (const float*)d_in[23];
  const float* W2s = (const float*)d_in[24]; const float* b2s = (const float*)d_in[25];
  const float* row_gamma   = (const float*)d_in[26];
  const float* row_beta    = (const float*)d_in[27];
  const float* token_gamma = (const float*)d_in[28];
  const float* token_beta  = (const float*)d_in[29];

  const int NR = in_sizes[0] / 256;   // 20000
  const int NT = in_sizes[1] / 256;   // 100000
  const int E  = in_sizes[2] / 2;     // 300000

  float* out_row = (float*)d_out;
  float* out_tok = (float*)d_out + (long long)NR * 256;

  void *pmega_, *pqs_, *pkv_, *peb1_, *peb2_, *pbfA_, *pbfB_,
       *pbfW_, *pbias_, *pdeg_, *prp_, *pcur_, *pperm_, *pbs_;
  hipGetSymbolAddress(&pmega_, HIP_SYMBOL(g_mega));
  hipGetSymbolAddress(&pqs_,   HIP_SYMBOL(g_qs));
  hipGetSymbolAddress(&pkv_,   HIP_SYMBOL(g_kv));
  hipGetSymbolAddress(&peb1_,  HIP_SYMBOL(g_eb1));
  hipGetSymbolAddress(&peb2_,  HIP_SYMBOL(g_eb2));
  hipGetSymbolAddress(&pbfA_,  HIP_SYMBOL(g_bfA));
  hipGetSymbolAddress(&pbfB_,  HIP_SYMBOL(g_bfB));
  hipGetSymbolAddress(&pbfW_,  HIP_SYMBOL(g_bfW));
  hipGetSymbolAddress(&pbias_, HIP_SYMBOL(g_bias));
  hipGetSymbolAddress(&pdeg_,  HIP_SYMBOL(g_deg));
  hipGetSymbolAddress(&prp_,   HIP_SYMBOL(g_rowptr));
  hipGetSymbolAddress(&pcur_,  HIP_SYMBOL(g_cur));
  hipGetSymbolAddress(&pperm_, HIP_SYMBOL(g_perm2));
  hipGetSymbolAddress(&pbs_,   HIP_SYMBOL(g_bsum));
  unsigned short* mega = (unsigned short*)pmega_;
  unsigned short* qs   = (unsigned short*)pqs_;
  unsigned short* kv   = (unsigned short*)pkv_;
  unsigned short* eb1  = (unsigned short*)peb1_;
  unsigned short* eb2  = (unsigned short*)peb2_;
  unsigned short* bfA  = (unsigned short*)pbfA_;
  unsigned short* bfB  = (unsigned short*)pbfB_;
  unsigned short* bfW  = (unsigned short*)pbfW_;
  float* gbias = (float*)pbias_;
  int*   deg   = (int*)pdeg_;
  int*   rp    = (int*)prp_;
  int*   cur   = (int*)pcur_;
  int2*  perm2 = (int2*)pperm_;
  int*   bsum  = (int*)pbs_;

  // Weight buffers (elements): Wmega@0 (1024x256), Wqs1@262144 (512x256),
  // Wkv2@393216 (512x256), We1@524288 (256x128), We2@557056 (256x128).
  unsigned short* Wmega = bfW + 0;
  unsigned short* Wqs1  = bfW + 262144;
  unsigned short* Wkv2  = bfW + 393216;
  unsigned short* We1   = bfW + 524288;
  unsigned short* We2   = bfW + 557056;
  wconv4<<<1024, 256, 0, stream>>>(P4{{W1k, W1v, W2q, W2s}}, Wmega, 256, 1024);
  wconv4<<<512, 256, 0, stream>>>(P4{{W1q, W1s, nullptr, nullptr}}, Wqs1, 256, 512);
  wconv4<<<512, 256, 0, stream>>>(P4{{W2k, W2v, nullptr, nullptr}}, Wkv2, 256, 512);
  wconv4<<<128, 256, 0, stream>>>(P4{{W1e, nullptr, nullptr, nullptr}}, We1, 128, 256);
  wconv4<<<128, 256, 0, stream>>>(P4{{W2e, nullptr, nullptr, nullptr}}, We2, 128, 256);
  // Bias layout: mega [b1k|b1v|b2q|b2s]@0, [b1q|b1s]@1024, [b2k|b2v]@1536,
  // b1e@2048, b2e@2304.
  P10 bp{{b1k, b1v, b2q, b2s, b1q, b1s, b2k, b2v, b1e, b2e}};
  bconcat<<<10, 256, 0, stream>>>(bp, gbias);

  // token_x f32 -> bf16 (mega's A; proven faster than in-GEMM cvt for K=256).
  conv_bf16<<<(int)(((long long)NT * 32 + 255) / 256), 256, 0, stream>>>(
      token_x, bfA, (long long)NT * 32);

  const int egrid = (E + 255) / 256;

  auto csr = [&](const int* ei, int Ndst) {
    hipMemsetAsync(deg, 0, (size_t)(Ndst + 1) * sizeof(int), stream);
    hist_kernel<<<egrid, 256, 0, stream>>>(ei, deg, E);
    int B = (Ndst + 255) / 256;
    scan1<<<B, 256, 0, stream>>>(deg, rp, bsum, Ndst);
    scan2<<<1, 512, 0, stream>>>(bsum, B);
    scan3<<<B, 256, 0, stream>>>(rp, bsum, deg, cur, Ndst);
    scatter_kernel<<<egrid, 256, 0, stream>>>(ei, cur, perm2, E);
  };

  // Swizzled 1-D grid size: ceil(nm/8)*8 * NC.
  auto swgrid = [](int M, int NC) {
    int nm = (M + 127) / 128;
    return (((nm + 7) / 8) * 8) * NC;
  };

  // ---------------- Projection GEMMs ----------------
  gemm_mfma<256, 1024, false><<<swgrid(NT, 8), 256, 0, stream>>>(
      bfA, Wmega, gbias + 0, mega, NT);                 // [k1|v1|q2|s2]
  gemm_mfma<256, 512, true><<<swgrid(NR, 4), 256, 0, stream>>>(
      row_x, Wqs1, gbias + 1024, qs, NR);               // [q1|s1]
  gemm_mfma<128, 256, true><<<swgrid(E, 2), 256, 0, stream>>>(
      ea1, We1, gbias + 2048, eb1, E);
  gemm_mfma<128, 256, true><<<swgrid(E, 2), 256, 0, stream>>>(
      ea2, We2, gbias + 2304, eb2, E);

  // ---------------- Phase 1: t2r ----------------
  csr(ei1, NR);
  fused_attn_ln<<<(NR + 7) / 8, 256, 0, stream>>>(rp, perm2,
                                                  qs, 512, mega, 1024, eb1,
                                                  row_x, row_gamma, row_beta,
                                                  out_row, bfB, NR);

  // ---------------- Phase 2: r2t ----------------
  gemm_mfma<256, 512, false><<<swgrid(NR, 4), 256, 0, stream>>>(
      bfB, Wkv2, gbias + 1536, kv, NR);                 // [k2|v2]
  csr(ei2, NT);
  fused_attn_ln<<<(NT + 7) / 8, 256, 0, stream>>>(rp, perm2,
                                                  mega + 512, 1024, kv, 512, eb2,
                                                  token_x, token_gamma, token_beta,
                                                  out_tok, nullptr, NT);
}